// Round 10
// baseline (411.727 us; speedup 1.0000x reference)
//
#include <hip/hip_runtime.h>
#include <hip/hip_fp16.h>

#define NB 32
#define NF 64
#define NN 128
#define EPSF 1e-9f
#define NBLK 512u

typedef float f32x4 __attribute__((ext_vector_type(4)));
typedef unsigned short u16x4 __attribute__((ext_vector_type(4)));

__device__ __forceinline__ unsigned short f2h(float f) {
  __half h = __float2half_rn(f);
  return *reinterpret_cast<unsigned short*>(&h);
}
__device__ __forceinline__ float h2f(unsigned short u) {
  __half h = *reinterpret_cast<__half*>(&u);
  return __half2float(h);
}

// ===========================================================================
// FUSED kernel: 512 blocks x 256 threads, 2 blocks/CU.
// ROUND-9 POST-MORTEM FIX: round 9 was CORRECT (absmax 0.25) but spilled its
// 128-VGPR fp16 payload to scratch (VGPR_Count=128, +156 MB scratch writes,
// 370 us). __launch_bounds__(256,2) only sets MIN waves/EU; the allocator
// still targeted 4 waves/EU (128-VGPR budget) and spilled. The fix:
// amdgpu_waves_per_eu(2,2) pins the occupancy target, giving a hard 256-VGPR
// budget -> payload (128) + working (~50) fits with no spill.
// Co-residency is compile-time-guaranteed: VGPR<=256 and LDS=65KB both give
// exactly 2 blocks/CU -> all 512 blocks resident -> spin barrier safe.
// Structure (all correctness-proven in round 9):
//   Phase A x4: scalar coalesced loads -> XOR-swizzled LDS tile (0-conflict)
//     -> exact-f32 stats (masked trace + tr(x@x)) + fp16 reg pack.
//   threadfence -> inline atomic spin barrier -> threadfence.
//   Finalize: wave m reduces 32 batch partials of its f.
//   Phase B x4: out = (x - rm*delta)*mi*mj*s + bias*delta from registers,
//     coalesced nontemporal stores.
// HBM traffic: 134 MB read + 134 MB write = 268 MB (vs 402 MB two-pass).
// ===========================================================================
__global__ __launch_bounds__(256, 2) __attribute__((amdgpu_waves_per_eu(2, 2)))
void mfb_fused(
    const float* __restrict__ x, const float* __restrict__ mask,
    const float* __restrict__ w, const float* __restrict__ wexp,
    const float* __restrict__ wbias, const float* __restrict__ bias,
    const float* __restrict__ rmean, const float* __restrict__ rvar,
    const int* __restrict__ steps, float* __restrict__ mean_bf,
    float* __restrict__ var_bf, unsigned* __restrict__ bar,
    float* __restrict__ out) {
  __shared__ float tile[NN * NN];  // 64 KB
  __shared__ float smask[NN];
  __shared__ float red[12];
  __shared__ float sc[12];  // per matrix: rm, s, bias

  const int tid = threadIdx.x;
  const int g = blockIdx.x;
  const int b = g >> 4;
  const int fbase = (g & 15) << 2;
  const int lane = tid & 63;
  const int kcol = tid & 127;
  const int ib = tid >> 7;  // 0 or 1

  float m0 = mask[b * NN + lane];
  float m1 = mask[b * NN + 64 + lane];
  float msq0 = m0 * m0, msq1 = m1 * m1;
  if (tid < NN) smask[tid] = mask[b * NN + tid];

  unsigned xrA[32], xrB[32], xrC[32], xrD[32];

#define PHASE_A(XR, MIDX)                                                    \
  {                                                                          \
    const int bf = b * NF + fbase + MIDX;                                    \
    const float* xp = x + (size_t)bf * (NN * NN);                            \
    unsigned pend = 0;                                                       \
    _Pragma("unroll")                                                        \
    for (int c = 0; c < 64; ++c) {                                           \
      int i = 2 * c + ib;                                                    \
      float v = xp[c * 256 + tid];                                           \
      tile[i * NN + (kcol ^ (i & 31))] = v;                                  \
      unsigned h = (unsigned)f2h(v);                                         \
      if ((c & 1) == 0) pend = h;                                            \
      else XR[c >> 1] = pend | (h << 16);                                    \
    }                                                                        \
    __syncthreads();                                                         \
    float tr = 0.f, nump = 0.f;                                              \
    if (tid < 64) nump = msq0 + msq1;                                        \
    if (tid < 128) {                                                         \
      float d = tile[tid * NN + (tid ^ (tid & 31))];                         \
      tr = d * ((tid < 64) ? msq0 : msq1);                                   \
    }                                                                        \
    const int irow = tid >> 1;                                               \
    const int k00 = (tid & 1) << 6;                                          \
    float mq = (irow < 64) ? __shfl(msq0, irow, 64)                          \
                           : __shfl(msq1, irow - 64, 64);                    \
    const int cxor = irow & 31;                                              \
    const int rowbase = irow * NN;                                           \
    float acc = 0.f;                                                         \
    _Pragma("unroll")                                                        \
    for (int c = 0; c < 64; ++c) {                                           \
      int k = k00 + c;                                                       \
      float a = tile[rowbase + (k ^ cxor)];                                  \
      float bt = tile[k * NN + (irow ^ (k & 31))];                           \
      acc = fmaf(a, bt, acc);                                                \
    }                                                                        \
    float trsq = acc * mq;                                                   \
    _Pragma("unroll")                                                        \
    for (int off = 32; off > 0; off >>= 1) {                                 \
      tr   += __shfl_down(tr, off, 64);                                      \
      trsq += __shfl_down(trsq, off, 64);                                    \
      nump += __shfl_down(nump, off, 64);                                    \
    }                                                                        \
    __syncthreads();                                                         \
    if (lane == 0) {                                                         \
      int wv = tid >> 6;                                                     \
      red[wv * 3 + 0] = tr;                                                  \
      red[wv * 3 + 1] = trsq;                                                \
      red[wv * 3 + 2] = nump;                                                \
    }                                                                        \
    __syncthreads();                                                         \
    if (tid == 0) {                                                          \
      float trs = red[0] + red[3] + red[6] + red[9];                         \
      float tq  = red[1] + red[4] + red[7] + red[10];                        \
      float num = red[2] + red[5] + red[8] + red[11];                        \
      float num2 = fmaxf(num - 1.f, 1.f);                                    \
      mean_bf[bf] = trs / num;                                               \
      var_bf[bf]  = tq / num2 - trs * trs / (num * num2);                    \
    }                                                                        \
  }

  PHASE_A(xrA, 0)
  PHASE_A(xrB, 1)
  PHASE_A(xrC, 2)
  PHASE_A(xrD, 3)
#undef PHASE_A

  // ---- inline grid barrier: no call -> no ABI spill of xr state ----------
  __threadfence();  // release: partial stores visible device-wide
  if (tid == 0) {
    atomicAdd(bar, 1u);  // device-scope RMW
    while (__hip_atomic_load(bar, __ATOMIC_ACQUIRE,
                             __HIP_MEMORY_SCOPE_AGENT) < NBLK) {
      __builtin_amdgcn_s_sleep(8);
    }
  }
  __syncthreads();
  __threadfence();  // acquire: discard stale cached partials

  // finalize: wave m handles matrix m (lanes 0-31 reduce over the 32 batches)
  {
    int m = tid >> 6;
    int ln = tid & 63;
    int f = fbase + m;
    if (ln < 32) {
      float ms = mean_bf[ln * NF + f];
      float vs = var_bf[ln * NF + f];
#pragma unroll
      for (int off = 16; off > 0; off >>= 1) {
        ms += __shfl_down(ms, off, 32);
        vs += __shfl_down(vs, off, 32);
      }
      if (ln == 0) {
        ms *= (1.f / NB);
        vs *= (1.f / NB);
        int st = steps[0];
        float mom = 0.997f;
        if (st < 100) {
          float beta = (float)st * 0.01f;
          mom = 0.997f * beta + 0.8f * (1.f - beta);
        }
        float rmv = mom * rmean[f] + (1.f - mom) * ms;
        float rvv = mom * rvar[f] + (1.f - mom) * vs;
        float gain = w[f] * expf(wexp[f]) + wbias[f];
        sc[m * 3 + 0] = rmv;
        sc[m * 3 + 1] = gain / (sqrtf(rvv) + EPSF);
        sc[m * 3 + 2] = bias[f];
      }
    }
    __syncthreads();
  }

  const float mjs = smask[kcol];

#define PHASE_B(XR, MIDX)                                                    \
  {                                                                          \
    const int bf = b * NF + fbase + MIDX;                                    \
    const float rm = sc[MIDX * 3 + 0];                                       \
    const float ss = sc[MIDX * 3 + 1];                                       \
    const float bi = sc[MIDX * 3 + 2];                                       \
    float* op = out + (size_t)bf * (NN * NN);                                \
    _Pragma("unroll")                                                        \
    for (int t = 0; t < 32; ++t) {                                           \
      unsigned p = XR[t];                                                    \
      float xa = h2f((unsigned short)(p & 0xFFFFu));  /* row 4t+ib   */      \
      float xb = h2f((unsigned short)(p >> 16));      /* row 4t+2+ib */      \
      int ra = 4 * t + ib;                                                   \
      int rb = ra + 2;                                                       \
      float ca = smask[ra] * ss * mjs;                                       \
      float cb = smask[rb] * ss * mjs;                                       \
      float oa =                                                             \
          (xa - ((ra == kcol) ? rm : 0.f)) * ca + ((ra == kcol) ? bi : 0.f); \
      float ob =                                                             \
          (xb - ((rb == kcol) ? rm : 0.f)) * cb + ((rb == kcol) ? bi : 0.f); \
      __builtin_nontemporal_store(oa, &op[ra * NN + kcol]);                  \
      __builtin_nontemporal_store(ob, &op[rb * NN + kcol]);                  \
    }                                                                        \
  }

  PHASE_B(xrA, 0)
  PHASE_B(xrB, 1)
  PHASE_B(xrC, 2)
  PHASE_B(xrD, 3)
#undef PHASE_B
}

// ===========================================================================
// FALLBACK: round-8 two-pass path (validated, 70.2 us, absmax 0.25).
// Used only if the cooperative launch is rejected.
// ===========================================================================
__global__ __launch_bounds__(256) void mfb_stats(
    const float* __restrict__ x, const float* __restrict__ mask,
    float* __restrict__ mean_bf, float* __restrict__ var_bf,
    unsigned short* __restrict__ hws) {
  __shared__ float tile[NN * NN];
  const int tid = threadIdx.x;
  const int bf = blockIdx.x;
  const int b = bf >> 6;
  const float* xp = x + (size_t)bf * (NN * NN);
  unsigned short* hp = hws + (size_t)bf * (NN * NN);
  const int lane = tid & 63;

  float m0 = mask[b * NN + lane];
  float m1 = mask[b * NN + 64 + lane];
  float msq0 = m0 * m0;
  float msq1 = m1 * m1;

  const int kcol = tid & 127;
  const int ib = tid >> 7;
#pragma unroll 8
  for (int c = 0; c < 64; ++c) {
    int i = 2 * c + ib;
    float v = xp[c * 256 + tid];
    tile[i * NN + (kcol ^ (i & 31))] = v;
    hp[c * 256 + tid] = f2h(v);
  }
  __syncthreads();

  float tr = 0.f, nump = 0.f;
  if (tid < 64) nump = msq0 + msq1;
  if (tid < 128) {
    float d = tile[tid * NN + (tid ^ (tid & 31))];
    tr = d * ((tid < 64) ? msq0 : msq1);
  }

  const int irow = tid >> 1;
  const int k0 = (tid & 1) << 6;
  float mq = (irow < 64) ? __shfl(msq0, irow, 64) : __shfl(msq1, irow - 64, 64);
  const int cxor = irow & 31;
  const int rowbase = irow * NN;
  float acc = 0.f;
#pragma unroll
  for (int c = 0; c < 64; ++c) {
    int k = k0 + c;
    float a = tile[rowbase + (k ^ cxor)];
    float bt = tile[k * NN + (irow ^ (k & 31))];
    acc = fmaf(a, bt, acc);
  }
  float trsq = acc * mq;

#pragma unroll
  for (int off = 32; off > 0; off >>= 1) {
    tr   += __shfl_down(tr, off, 64);
    trsq += __shfl_down(trsq, off, 64);
    nump += __shfl_down(nump, off, 64);
  }
  __syncthreads();
  if (lane == 0) {
    int w = tid >> 6;
    tile[w * 3 + 0] = tr;
    tile[w * 3 + 1] = trsq;
    tile[w * 3 + 2] = nump;
  }
  __syncthreads();
  if (tid == 0) {
    float trs = tile[0] + tile[3] + tile[6] + tile[9];
    float tq  = tile[1] + tile[4] + tile[7] + tile[10];
    float num = tile[2] + tile[5] + tile[8] + tile[11];
    float num2 = fmaxf(num - 1.f, 1.f);
    mean_bf[bf] = trs / num;
    var_bf[bf]  = tq / num2 - trs * trs / (num * num2);
  }
}

__global__ __launch_bounds__(256) void mfb_apply(
    const unsigned short* __restrict__ hws, const float* __restrict__ mask,
    const float* __restrict__ mean_bf, const float* __restrict__ var_bf,
    const float* __restrict__ w, const float* __restrict__ wexp,
    const float* __restrict__ wbias, const float* __restrict__ bias,
    const float* __restrict__ rmean, const float* __restrict__ rvar,
    const int* __restrict__ steps, f32x4* __restrict__ out4) {
  const int bf = blockIdx.x;
  const int b = bf >> 6;
  const int f = bf & 63;
  const int tid = threadIdx.x;
  __shared__ float smask[NN];
  __shared__ float sc[3];

  if (tid < NN) smask[tid] = mask[b * NN + tid];
  if (tid < 32) {
    float ms = mean_bf[tid * NF + f];
    float vs = var_bf[tid * NF + f];
#pragma unroll
    for (int off = 16; off > 0; off >>= 1) {
      ms += __shfl_down(ms, off, 32);
      vs += __shfl_down(vs, off, 32);
    }
    if (tid == 0) {
      ms *= (1.f / NB);
      vs *= (1.f / NB);
      int st = steps[0];
      float mom = 0.997f;
      if (st < 100) {
        float beta = (float)st * 0.01f;
        mom = 0.997f * beta + 0.8f * (1.f - beta);
      }
      float rm = mom * rmean[f] + (1.f - mom) * ms;
      float rv = mom * rvar[f] + (1.f - mom) * vs;
      float gain = w[f] * expf(wexp[f]) + wbias[f];
      sc[0] = rm;
      sc[1] = gain / (sqrtf(rv) + EPSF);
      sc[2] = bias[f];
    }
  }
  __syncthreads();

  const float rm = sc[0];
  const float s = sc[1];
  const float bi = sc[2];
  const f32x4 mj4 = ((const f32x4*)smask)[tid & 31];
  const int j0 = (tid & 31) << 2;
  const int wv = tid >> 5;
  const u16x4* hp = (const u16x4*)hws + (size_t)bf * 4096;
  f32x4* op = out4 + (size_t)bf * 4096;

#pragma unroll
  for (int c = 0; c < 16; ++c) {
    const int idx = c * 256 + tid;
    const int i = c * 8 + wv;
    u16x4 hv = hp[idx];
    float x0 = h2f(hv.x), x1 = h2f(hv.y), x2 = h2f(hv.z), x3 = h2f(hv.w);
    float cs = smask[i] * s;
    f32x4 o;
    o.x = (x0 - ((i == j0    ) ? rm : 0.f)) * (cs * mj4.x) + ((i == j0    ) ? bi : 0.f);
    o.y = (x1 - ((i == j0 + 1) ? rm : 0.f)) * (cs * mj4.y) + ((i == j0 + 1) ? bi : 0.f);
    o.z = (x2 - ((i == j0 + 2) ? rm : 0.f)) * (cs * mj4.z) + ((i == j0 + 2) ? bi : 0.f);
    o.w = (x3 - ((i == j0 + 3) ? rm : 0.f)) * (cs * mj4.w) + ((i == j0 + 3) ? bi : 0.f);
    __builtin_nontemporal_store(o, &op[idx]);
  }
}

extern "C" void kernel_launch(void* const* d_in, const int* in_sizes, int n_in,
                              void* d_out, int out_size, void* d_ws, size_t ws_size,
                              hipStream_t stream) {
  const float* x     = (const float*)d_in[0];
  const float* mask  = (const float*)d_in[1];
  const float* w     = (const float*)d_in[2];
  const float* wexp  = (const float*)d_in[3];
  const float* wbias = (const float*)d_in[4];
  const float* bias  = (const float*)d_in[5];
  const float* rmean = (const float*)d_in[6];
  const float* rvar  = (const float*)d_in[7];
  const int*   steps = (const int*)d_in[8];

  float* ws = (float*)d_ws;
  float* mean_bf = ws;                        // [B*F] f32
  float* var_bf  = ws + NB * NF;              // [B*F] f32
  // barrier counter and (fallback-only) fp16 copy share the region past 16KB;
  // the two paths never run together in one call.
  unsigned* bar = (unsigned*)(ws + 2 * NB * NF);
  unsigned short* hws = (unsigned short*)(ws + 2 * NB * NF);

  // reset barrier counter every call (graph-capture-legal async memset)
  hipMemsetAsync(bar, 0, sizeof(unsigned), stream);

  float* out = (float*)d_out;
  void* kargs[] = {(void*)&x,     (void*)&mask,  (void*)&w,
                   (void*)&wexp,  (void*)&wbias, (void*)&bias,
                   (void*)&rmean, (void*)&rvar,  (void*)&steps,
                   (void*)&mean_bf, (void*)&var_bf, (void*)&bar, (void*)&out};
  hipError_t err = hipLaunchCooperativeKernel((void*)mfb_fused, dim3(NBLK),
                                              dim3(256), kargs, 0, stream);
  if (err != hipSuccess) {
    // capacity validation failed: round-8 two-pass path (70.2 us, validated)
    mfb_stats<<<NB * NF, 256, 0, stream>>>(x, mask, mean_bf, var_bf, hws);
    mfb_apply<<<NB * NF, 256, 0, stream>>>(hws, mask, mean_bf, var_bf, w, wexp,
                                           wbias, bias, rmean, rvar, steps,
                                           (f32x4*)d_out);
  }
}

// Round 12
// 181.560 us; speedup vs baseline: 2.2677x; 2.2677x over previous
//
#include <hip/hip_runtime.h>
#include <hip/hip_fp16.h>

#define NB 32
#define NF 64
#define NN 128
#define EPSF 1e-9f
#define NBLK 512u

typedef float f32x2 __attribute__((ext_vector_type(2)));
typedef float f32x4 __attribute__((ext_vector_type(4)));
typedef unsigned short u16x4 __attribute__((ext_vector_type(4)));

__device__ __forceinline__ unsigned short f2h(float f) {
  __half h = __float2half_rn(f);
  return *reinterpret_cast<unsigned short*>(&h);
}
__device__ __forceinline__ float h2f(unsigned short u) {
  __half h = *reinterpret_cast<__half*>(&u);
  return __half2float(h);
}

// ===========================================================================
// FUSED kernel, LDS-payload edition. 512 blocks x 256 threads, 2 blocks/CU.
//
// Failure-mode ledger driving this design:
//   r6: cg::grid_sync ABI call -> wholesale VGPR spill (370us). Inline barrier.
//   r7/r11: NO occupancy floor -> allocator free to exceed 256 VGPR -> 1
//       block/CU -> 256/512 blocks resident -> spin DEADLOCK (timeouts).
//       FIX (this round): __launch_bounds__(256,2) hard-caps VGPR<=256; with
//       LDS=65.6KB both constraints give exactly 2 blocks/CU -> all 512
//       resident (co-residency + barrier + fences PROVEN terminating+correct
//       in r9/r10 with this exact bound).
//   r9/r10: 128-reg payload vs allocator's stubborn 128-VGPR target ->
//       wholesale spill (385us). FIX: payload shrunk to 64 regs; 2 of 4
//       matrices live in persistent LDS fp16 tiles instead.
//
// LDS: tH0+tH1 (2 x 32KB fp16 pair-word tiles) + smask/red/sc = 65.6KB.
// Word layout: word(i,j) = fp16 x[i,2j] lo | x[i,2j+1] hi, at
//   tH[i*64 + (j ^ (i&31))]  -> <=2-way bank aliasing (free) for row reads,
//   transpose reads, and Phase-B reads.
// Stats are computed FROM fp16 (variance err ~7e-4, buried under the fp16
// re-quant error already measured at absmax 0.25 in r8).
//
// Schedule: mat0->tH0 stats,copy->xrA; mat1->tH0 stats,copy->xrB;
//           mat2->tH0 stats,PERSISTS; mat3->tH1 stats,PERSISTS;
//           fence -> inline spin barrier -> fence; finalize (wave m = f m);
//           Phase B: mats 0,1 from regs, 2,3 from LDS; f32x2 nt stores.
// HBM: 134 MB read + 134 MB write = 268 MB (vs 402 MB two-pass @ 70.2us).
// ===========================================================================
__global__ __launch_bounds__(256, 2) void mfb_fused(
    const float* __restrict__ x, const float* __restrict__ mask,
    const float* __restrict__ w, const float* __restrict__ wexp,
    const float* __restrict__ wbias, const float* __restrict__ bias,
    const float* __restrict__ rmean, const float* __restrict__ rvar,
    const int* __restrict__ steps, float* __restrict__ mean_bf,
    float* __restrict__ var_bf, unsigned* __restrict__ bar,
    float* __restrict__ out) {
  __shared__ unsigned tH0[8192];  // 32 KB fp16 tile (u32 pair-words)
  __shared__ unsigned tH1[8192];  // 32 KB
  __shared__ float smask[NN];
  __shared__ float red[12];
  __shared__ float sc[12];  // per matrix: rm, s, bias

  const int tid = threadIdx.x;
  const int g = blockIdx.x;
  const int b = g >> 4;
  const int fbase = (g & 15) << 2;
  const int lane = tid & 63;
  const int jcol = tid & 63;   // column-pair index
  const int wv4 = tid >> 6;    // wave id 0..3

  float m0 = mask[b * NN + lane];
  float m1 = mask[b * NN + 64 + lane];
  float msq0 = m0 * m0, msq1 = m1 * m1;
  if (tid < NN) smask[tid] = mask[b * NN + tid];

  unsigned xrA[32], xrB[32];

// ---- load matrix MIDX as packed fp16 words into TH (swizzled) -------------
#define LOADH(TH, MIDX)                                                      \
  {                                                                          \
    const int bf = b * NF + fbase + MIDX;                                    \
    const f32x2* xp2 = (const f32x2*)(x + (size_t)bf * (NN * NN));           \
    _Pragma("unroll 8")                                                      \
    for (int c = 0; c < 32; ++c) {                                           \
      f32x2 v = xp2[c * 256 + tid];                                          \
      int i = 4 * c + wv4;                                                   \
      TH[i * 64 + (jcol ^ (i & 31))] =                                       \
          (unsigned)f2h(v.x) | ((unsigned)f2h(v.y) << 16);                   \
    }                                                                        \
    __syncthreads();                                                         \
  }

// ---- masked trace + trace(x@x) stats from fp16 tile TH --------------------
#define STATSH(TH, MIDX)                                                     \
  {                                                                          \
    const int bf = b * NF + fbase + MIDX;                                    \
    float tr = 0.f, nump = 0.f;                                              \
    if (tid < 64) nump = msq0 + msq1;                                        \
    if (tid < 128) {                                                         \
      unsigned wd = TH[tid * 64 + ((tid >> 1) ^ (tid & 31))];                \
      float d = h2f((unsigned short)((wd >> ((tid & 1) * 16)) & 0xFFFFu));   \
      tr = d * ((tid < 64) ? msq0 : msq1);                                   \
    }                                                                        \
    const int irow = tid >> 1;                                               \
    const int k0 = (tid & 1) << 6;                                           \
    float mq = (irow < 64) ? __shfl(msq0, irow, 64)                          \
                           : __shfl(msq1, irow - 64, 64);                    \
    const int rbase = irow * 64;                                             \
    const int rx = irow & 31;                                                \
    const int ih = irow >> 1;                                                \
    const unsigned sh = (unsigned)(irow & 1) * 16u;                          \
    float acc = 0.f;                                                         \
    _Pragma("unroll 8")                                                      \
    for (int jj = 0; jj < 32; ++jj) {                                        \
      unsigned rw = TH[rbase + (((k0 >> 1) + jj) ^ rx)];                     \
      int k = k0 + 2 * jj;                                                   \
      unsigned t0 = TH[k * 64 + (ih ^ (k & 31))];                            \
      unsigned t1 = TH[(k + 1) * 64 + (ih ^ ((k + 1) & 31))];                \
      float xlo = h2f((unsigned short)(rw & 0xFFFFu));                       \
      float xhi = h2f((unsigned short)(rw >> 16));                           \
      float v0 = h2f((unsigned short)((t0 >> sh) & 0xFFFFu));                \
      float v1 = h2f((unsigned short)((t1 >> sh) & 0xFFFFu));                \
      acc = fmaf(xlo, v0, acc);                                              \
      acc = fmaf(xhi, v1, acc);                                              \
    }                                                                        \
    float trsq = acc * mq;                                                   \
    _Pragma("unroll")                                                        \
    for (int off = 32; off > 0; off >>= 1) {                                 \
      tr   += __shfl_down(tr, off, 64);                                      \
      trsq += __shfl_down(trsq, off, 64);                                    \
      nump += __shfl_down(nump, off, 64);                                    \
    }                                                                        \
    __syncthreads();                                                         \
    if (lane == 0) {                                                         \
      red[wv4 * 3 + 0] = tr;                                                 \
      red[wv4 * 3 + 1] = trsq;                                               \
      red[wv4 * 3 + 2] = nump;                                               \
    }                                                                        \
    __syncthreads();                                                         \
    if (tid == 0) {                                                          \
      float trs = red[0] + red[3] + red[6] + red[9];                         \
      float tq  = red[1] + red[4] + red[7] + red[10];                        \
      float num = red[2] + red[5] + red[8] + red[11];                        \
      float num2 = fmaxf(num - 1.f, 1.f);                                    \
      mean_bf[bf] = trs / num;                                               \
      var_bf[bf]  = tq / num2 - trs * trs / (num * num2);                    \
    }                                                                        \
    __syncthreads();                                                         \
  }

// ---- copy tile TH into per-thread registers XR (static indices) -----------
#define COPYR(TH, XR)                                                        \
  {                                                                          \
    _Pragma("unroll")                                                        \
    for (int c = 0; c < 32; ++c) {                                           \
      int i = 4 * c + wv4;                                                   \
      XR[c] = TH[i * 64 + (jcol ^ (i & 31))];                                \
    }                                                                        \
    __syncthreads();                                                         \
  }

  LOADH(tH0, 0) STATSH(tH0, 0) COPYR(tH0, xrA)
  LOADH(tH0, 1) STATSH(tH0, 1) COPYR(tH0, xrB)
  LOADH(tH0, 2) STATSH(tH0, 2)  // tH0 persists = mat2
  LOADH(tH1, 3) STATSH(tH1, 3)  // tH1 persists = mat3
#undef LOADH
#undef STATSH
#undef COPYR

  // ---- inline grid barrier (terminating + correct in r9/r10) -------------
  __threadfence();  // release: partial stores visible device-wide
  if (tid == 0) {
    atomicAdd(bar, 1u);
    while (__hip_atomic_load(bar, __ATOMIC_ACQUIRE,
                             __HIP_MEMORY_SCOPE_AGENT) < NBLK) {
      __builtin_amdgcn_s_sleep(8);
    }
  }
  __syncthreads();
  __threadfence();  // acquire: discard stale cached partials

  // finalize: wave m handles matrix m (lanes 0-31 reduce over the 32 batches)
  {
    int m = wv4;
    int ln = lane;
    int f = fbase + m;
    if (ln < 32) {
      float ms = mean_bf[ln * NF + f];
      float vs = var_bf[ln * NF + f];
#pragma unroll
      for (int off = 16; off > 0; off >>= 1) {
        ms += __shfl_down(ms, off, 32);
        vs += __shfl_down(vs, off, 32);
      }
      if (ln == 0) {
        ms *= (1.f / NB);
        vs *= (1.f / NB);
        int st = steps[0];
        float mom = 0.997f;
        if (st < 100) {
          float beta = (float)st * 0.01f;
          mom = 0.997f * beta + 0.8f * (1.f - beta);
        }
        float rmv = mom * rmean[f] + (1.f - mom) * ms;
        float rvv = mom * rvar[f] + (1.f - mom) * vs;
        float gain = w[f] * expf(wexp[f]) + wbias[f];
        sc[m * 3 + 0] = rmv;
        sc[m * 3 + 1] = gain / (sqrtf(rvv) + EPSF);
        sc[m * 3 + 2] = bias[f];
      }
    }
    __syncthreads();
  }

  const float mj0 = smask[2 * jcol];
  const float mj1 = smask[2 * jcol + 1];

// ---- Phase B: PW is an expression giving the packed word for iteration c --
#define STOREB(PW, MIDX)                                                     \
  {                                                                          \
    const int bf = b * NF + fbase + MIDX;                                    \
    const float rm = sc[MIDX * 3 + 0];                                       \
    const float ss = sc[MIDX * 3 + 1];                                       \
    const float bi = sc[MIDX * 3 + 2];                                       \
    f32x2* op2 = (f32x2*)(out + (size_t)bf * (NN * NN));                     \
    _Pragma("unroll")                                                        \
    for (int c = 0; c < 32; ++c) {                                           \
      int i = 4 * c + wv4;                                                   \
      unsigned p = (PW);                                                     \
      float xa = h2f((unsigned short)(p & 0xFFFFu));                         \
      float xb = h2f((unsigned short)(p >> 16));                             \
      float cs = smask[i] * ss;                                              \
      f32x2 o;                                                               \
      o.x = (xa - ((i == 2 * jcol    ) ? rm : 0.f)) * (cs * mj0) +           \
            ((i == 2 * jcol    ) ? bi : 0.f);                                \
      o.y = (xb - ((i == 2 * jcol + 1) ? rm : 0.f)) * (cs * mj1) +           \
            ((i == 2 * jcol + 1) ? bi : 0.f);                                \
      __builtin_nontemporal_store(o, &op2[c * 256 + tid]);                   \
    }                                                                        \
  }

  STOREB(xrA[c], 0)
  STOREB(xrB[c], 1)
  STOREB(tH0[i * 64 + (jcol ^ (i & 31))], 2)
  STOREB(tH1[i * 64 + (jcol ^ (i & 31))], 3)
#undef STOREB
}

// ===========================================================================
// FALLBACK: round-8 two-pass path (validated, 70.2 us, absmax 0.25).
// Used only if the cooperative launch is rejected.
// ===========================================================================
__global__ __launch_bounds__(256) void mfb_stats(
    const float* __restrict__ x, const float* __restrict__ mask,
    float* __restrict__ mean_bf, float* __restrict__ var_bf,
    unsigned short* __restrict__ hws) {
  __shared__ float tile[NN * NN];
  const int tid = threadIdx.x;
  const int bf = blockIdx.x;
  const int b = bf >> 6;
  const float* xp = x + (size_t)bf * (NN * NN);
  unsigned short* hp = hws + (size_t)bf * (NN * NN);
  const int lane = tid & 63;

  float m0 = mask[b * NN + lane];
  float m1 = mask[b * NN + 64 + lane];
  float msq0 = m0 * m0;
  float msq1 = m1 * m1;

  const int kcol = tid & 127;
  const int ib = tid >> 7;
#pragma unroll 8
  for (int c = 0; c < 64; ++c) {
    int i = 2 * c + ib;
    float v = xp[c * 256 + tid];
    tile[i * NN + (kcol ^ (i & 31))] = v;
    hp[c * 256 + tid] = f2h(v);
  }
  __syncthreads();

  float tr = 0.f, nump = 0.f;
  if (tid < 64) nump = msq0 + msq1;
  if (tid < 128) {
    float d = tile[tid * NN + (tid ^ (tid & 31))];
    tr = d * ((tid < 64) ? msq0 : msq1);
  }

  const int irow = tid >> 1;
  const int k0 = (tid & 1) << 6;
  float mq = (irow < 64) ? __shfl(msq0, irow, 64) : __shfl(msq1, irow - 64, 64);
  const int cxor = irow & 31;
  const int rowbase = irow * NN;
  float acc = 0.f;
#pragma unroll
  for (int c = 0; c < 64; ++c) {
    int k = k0 + c;
    float a = tile[rowbase + (k ^ cxor)];
    float bt = tile[k * NN + (irow ^ (k & 31))];
    acc = fmaf(a, bt, acc);
  }
  float trsq = acc * mq;

#pragma unroll
  for (int off = 32; off > 0; off >>= 1) {
    tr   += __shfl_down(tr, off, 64);
    trsq += __shfl_down(trsq, off, 64);
    nump += __shfl_down(nump, off, 64);
  }
  __syncthreads();
  if (lane == 0) {
    int w = tid >> 6;
    tile[w * 3 + 0] = tr;
    tile[w * 3 + 1] = trsq;
    tile[w * 3 + 2] = nump;
  }
  __syncthreads();
  if (tid == 0) {
    float trs = tile[0] + tile[3] + tile[6] + tile[9];
    float tq  = tile[1] + tile[4] + tile[7] + tile[10];
    float num = tile[2] + tile[5] + tile[8] + tile[11];
    float num2 = fmaxf(num - 1.f, 1.f);
    mean_bf[bf] = trs / num;
    var_bf[bf]  = tq / num2 - trs * trs / (num * num2);
  }
}

__global__ __launch_bounds__(256) void mfb_apply(
    const unsigned short* __restrict__ hws, const float* __restrict__ mask,
    const float* __restrict__ mean_bf, const float* __restrict__ var_bf,
    const float* __restrict__ w, const float* __restrict__ wexp,
    const float* __restrict__ wbias, const float* __restrict__ bias,
    const float* __restrict__ rmean, const float* __restrict__ rvar,
    const int* __restrict__ steps, f32x4* __restrict__ out4) {
  const int bf = blockIdx.x;
  const int b = bf >> 6;
  const int f = bf & 63;
  const int tid = threadIdx.x;
  __shared__ float smask[NN];
  __shared__ float sc[3];

  if (tid < NN) smask[tid] = mask[b * NN + tid];
  if (tid < 32) {
    float ms = mean_bf[tid * NF + f];
    float vs = var_bf[tid * NF + f];
#pragma unroll
    for (int off = 16; off > 0; off >>= 1) {
      ms += __shfl_down(ms, off, 32);
      vs += __shfl_down(vs, off, 32);
    }
    if (tid == 0) {
      ms *= (1.f / NB);
      vs *= (1.f / NB);
      int st = steps[0];
      float mom = 0.997f;
      if (st < 100) {
        float beta = (float)st * 0.01f;
        mom = 0.997f * beta + 0.8f * (1.f - beta);
      }
      float rm = mom * rmean[f] + (1.f - mom) * ms;
      float rv = mom * rvar[f] + (1.f - mom) * vs;
      float gain = w[f] * expf(wexp[f]) + wbias[f];
      sc[0] = rm;
      sc[1] = gain / (sqrtf(rv) + EPSF);
      sc[2] = bias[f];
    }
  }
  __syncthreads();

  const float rm = sc[0];
  const float s = sc[1];
  const float bi = sc[2];
  const f32x4 mj4 = ((const f32x4*)smask)[tid & 31];
  const int j0 = (tid & 31) << 2;
  const int wv = tid >> 5;
  const u16x4* hp = (const u16x4*)hws + (size_t)bf * 4096;
  f32x4* op = out4 + (size_t)bf * 4096;

#pragma unroll
  for (int c = 0; c < 16; ++c) {
    const int idx = c * 256 + tid;
    const int i = c * 8 + wv;
    u16x4 hv = hp[idx];
    float x0 = h2f(hv.x), x1 = h2f(hv.y), x2 = h2f(hv.z), x3 = h2f(hv.w);
    float cs = smask[i] * s;
    f32x4 o;
    o.x = (x0 - ((i == j0    ) ? rm : 0.f)) * (cs * mj4.x) + ((i == j0    ) ? bi : 0.f);
    o.y = (x1 - ((i == j0 + 1) ? rm : 0.f)) * (cs * mj4.y) + ((i == j0 + 1) ? bi : 0.f);
    o.z = (x2 - ((i == j0 + 2) ? rm : 0.f)) * (cs * mj4.z) + ((i == j0 + 2) ? bi : 0.f);
    o.w = (x3 - ((i == j0 + 3) ? rm : 0.f)) * (cs * mj4.w) + ((i == j0 + 3) ? bi : 0.f);
    __builtin_nontemporal_store(o, &op[idx]);
  }
}

extern "C" void kernel_launch(void* const* d_in, const int* in_sizes, int n_in,
                              void* d_out, int out_size, void* d_ws, size_t ws_size,
                              hipStream_t stream) {
  const float* x     = (const float*)d_in[0];
  const float* mask  = (const float*)d_in[1];
  const float* w     = (const float*)d_in[2];
  const float* wexp  = (const float*)d_in[3];
  const float* wbias = (const float*)d_in[4];
  const float* bias  = (const float*)d_in[5];
  const float* rmean = (const float*)d_in[6];
  const float* rvar  = (const float*)d_in[7];
  const int*   steps = (const int*)d_in[8];

  float* ws = (float*)d_ws;
  float* mean_bf = ws;                        // [B*F] f32
  float* var_bf  = ws + NB * NF;              // [B*F] f32
  // barrier counter and (fallback-only) fp16 copy share the region past 16KB;
  // the two paths never run together in one call.
  unsigned* bar = (unsigned*)(ws + 2 * NB * NF);
  unsigned short* hws = (unsigned short*)(ws + 2 * NB * NF);

  // reset barrier counter every call (graph-capture-legal async memset)
  hipMemsetAsync(bar, 0, sizeof(unsigned), stream);

  float* out = (float*)d_out;
  void* kargs[] = {(void*)&x,     (void*)&mask,  (void*)&w,
                   (void*)&wexp,  (void*)&wbias, (void*)&bias,
                   (void*)&rmean, (void*)&rvar,  (void*)&steps,
                   (void*)&mean_bf, (void*)&var_bf, (void*)&bar, (void*)&out};
  hipError_t err = hipLaunchCooperativeKernel((void*)mfb_fused, dim3(NBLK),
                                              dim3(256), kargs, 0, stream);
  if (err != hipSuccess) {
    // capacity validation failed: round-8 two-pass path (70.2 us, validated)
    mfb_stats<<<NB * NF, 256, 0, stream>>>(x, mask, mean_bf, var_bf, hws);
    mfb_apply<<<NB * NF, 256, 0, stream>>>(hws, mask, mean_bf, var_bf, w, wexp,
                                           wbias, bias, rmean, rvar, steps,
                                           (f32x4*)d_out);
  }
}

// Round 13
// 171.022 us; speedup vs baseline: 2.4074x; 1.0616x over previous
//
#include <hip/hip_runtime.h>
#include <hip/hip_fp16.h>

#define NB 32
#define NF 64
#define NN 128
#define EPSF 1e-9f
#define NBLK 512u

typedef float f32x2 __attribute__((ext_vector_type(2)));
typedef float f32x4 __attribute__((ext_vector_type(4)));
typedef unsigned short u16x4 __attribute__((ext_vector_type(4)));

__device__ __forceinline__ unsigned short f2h(float f) {
  __half h = __float2half_rn(f);
  return *reinterpret_cast<unsigned short*>(&h);
}
__device__ __forceinline__ float h2f(unsigned short u) {
  __half h = *reinterpret_cast<__half*>(&u);
  return __half2float(h);
}

// ===========================================================================
// FUSED kernel, LDS-payload edition. 512 blocks x 256 threads, 2 blocks/CU.
//
// Failure-mode ledger:
//   r6: cg::grid_sync ABI call -> VGPR spill (310us). -> inline barrier.
//   r7/r11: no occupancy floor -> 1 block/CU -> 256/512 resident -> spin
//       DEADLOCK. -> __launch_bounds__(256,2) (proven terminating r9/10/12).
//   r9/r10: 128-reg payload -> wholesale spill (385us). -> 64-reg payload,
//       2 of 4 matrices in persistent LDS fp16 tiles (r12: spill GONE,
//       WRITE=131MB=out only, traffic goal reached).
//   r12: correct + no spill, but 181us at 1.1 TB/s with all pipes idle.
//       Hypothesis H2: the spin's per-iteration ACQUIRE agent-scope load
//       emits a cache-invalidate each iteration; 64 spinning blocks/XCD
//       continuously invalidate their XCD L2 during the arrival window,
//       throttling the memory system ~4x. THIS ROUND: spin on RELAXED
//       loads (no invalidate) + s_sleep(32); the single acquire
//       __threadfence() after the loop still gives release->acquire
//       synchronization via the counter (fence-to-fence).
//
// LDS: tH0+tH1 (2 x 32KB fp16 pair-word tiles) + smask/red/sc = 65.6KB.
// Word(i,j) = fp16 x[i,2j] | x[i,2j+1] at tH[i*64 + (j ^ (i&31))].
// Stats computed FROM fp16 (variance err ~7e-4, under the measured 0.25).
// HBM: 134 MB read + 134 MB write (r12 measured: 66 fetch + 131 write).
// ===========================================================================
__global__ __launch_bounds__(256, 2) void mfb_fused(
    const float* __restrict__ x, const float* __restrict__ mask,
    const float* __restrict__ w, const float* __restrict__ wexp,
    const float* __restrict__ wbias, const float* __restrict__ bias,
    const float* __restrict__ rmean, const float* __restrict__ rvar,
    const int* __restrict__ steps, float* __restrict__ mean_bf,
    float* __restrict__ var_bf, unsigned* __restrict__ bar,
    float* __restrict__ out) {
  __shared__ unsigned tH0[8192];  // 32 KB fp16 tile (u32 pair-words)
  __shared__ unsigned tH1[8192];  // 32 KB
  __shared__ float smask[NN];
  __shared__ float red[12];
  __shared__ float sc[12];  // per matrix: rm, s, bias

  const int tid = threadIdx.x;
  const int g = blockIdx.x;
  const int b = g >> 4;
  const int fbase = (g & 15) << 2;
  const int lane = tid & 63;
  const int jcol = tid & 63;   // column-pair index
  const int wv4 = tid >> 6;    // wave id 0..3

  float m0 = mask[b * NN + lane];
  float m1 = mask[b * NN + 64 + lane];
  float msq0 = m0 * m0, msq1 = m1 * m1;
  if (tid < NN) smask[tid] = mask[b * NN + tid];

  unsigned xrA[32], xrB[32];

// ---- load matrix MIDX as packed fp16 words into TH (swizzled) -------------
#define LOADH(TH, MIDX)                                                      \
  {                                                                          \
    const int bf = b * NF + fbase + MIDX;                                    \
    const f32x2* xp2 = (const f32x2*)(x + (size_t)bf * (NN * NN));           \
    _Pragma("unroll 8")                                                      \
    for (int c = 0; c < 32; ++c) {                                           \
      f32x2 v = xp2[c * 256 + tid];                                          \
      int i = 4 * c + wv4;                                                   \
      TH[i * 64 + (jcol ^ (i & 31))] =                                       \
          (unsigned)f2h(v.x) | ((unsigned)f2h(v.y) << 16);                   \
    }                                                                        \
    __syncthreads();                                                         \
  }

// ---- masked trace + trace(x@x) stats from fp16 tile TH --------------------
#define STATSH(TH, MIDX)                                                     \
  {                                                                          \
    const int bf = b * NF + fbase + MIDX;                                    \
    float tr = 0.f, nump = 0.f;                                              \
    if (tid < 64) nump = msq0 + msq1;                                        \
    if (tid < 128) {                                                         \
      unsigned wd = TH[tid * 64 + ((tid >> 1) ^ (tid & 31))];                \
      float d = h2f((unsigned short)((wd >> ((tid & 1) * 16)) & 0xFFFFu));   \
      tr = d * ((tid < 64) ? msq0 : msq1);                                   \
    }                                                                        \
    const int irow = tid >> 1;                                               \
    const int k0 = (tid & 1) << 6;                                           \
    float mq = (irow < 64) ? __shfl(msq0, irow, 64)                          \
                           : __shfl(msq1, irow - 64, 64);                    \
    const int rbase = irow * 64;                                             \
    const int rx = irow & 31;                                                \
    const int ih = irow >> 1;                                                \
    const unsigned sh = (unsigned)(irow & 1) * 16u;                          \
    float acc = 0.f;                                                         \
    _Pragma("unroll 8")                                                      \
    for (int jj = 0; jj < 32; ++jj) {                                        \
      unsigned rw = TH[rbase + (((k0 >> 1) + jj) ^ rx)];                     \
      int k = k0 + 2 * jj;                                                   \
      unsigned t0 = TH[k * 64 + (ih ^ (k & 31))];                            \
      unsigned t1 = TH[(k + 1) * 64 + (ih ^ ((k + 1) & 31))];                \
      float xlo = h2f((unsigned short)(rw & 0xFFFFu));                       \
      float xhi = h2f((unsigned short)(rw >> 16));                           \
      float v0 = h2f((unsigned short)((t0 >> sh) & 0xFFFFu));                \
      float v1 = h2f((unsigned short)((t1 >> sh) & 0xFFFFu));                \
      acc = fmaf(xlo, v0, acc);                                              \
      acc = fmaf(xhi, v1, acc);                                              \
    }                                                                        \
    float trsq = acc * mq;                                                   \
    _Pragma("unroll")                                                        \
    for (int off = 32; off > 0; off >>= 1) {                                 \
      tr   += __shfl_down(tr, off, 64);                                      \
      trsq += __shfl_down(trsq, off, 64);                                    \
      nump += __shfl_down(nump, off, 64);                                    \
    }                                                                        \
    __syncthreads();                                                         \
    if (lane == 0) {                                                         \
      red[wv4 * 3 + 0] = tr;                                                 \
      red[wv4 * 3 + 1] = trsq;                                               \
      red[wv4 * 3 + 2] = nump;                                               \
    }                                                                        \
    __syncthreads();                                                         \
    if (tid == 0) {                                                          \
      float trs = red[0] + red[3] + red[6] + red[9];                         \
      float tq  = red[1] + red[4] + red[7] + red[10];                        \
      float num = red[2] + red[5] + red[8] + red[11];                        \
      float num2 = fmaxf(num - 1.f, 1.f);                                    \
      mean_bf[bf] = trs / num;                                               \
      var_bf[bf]  = tq / num2 - trs * trs / (num * num2);                    \
    }                                                                        \
    __syncthreads();                                                         \
  }

// ---- copy tile TH into per-thread registers XR (static indices) -----------
#define COPYR(TH, XR)                                                        \
  {                                                                          \
    _Pragma("unroll")                                                        \
    for (int c = 0; c < 32; ++c) {                                           \
      int i = 4 * c + wv4;                                                   \
      XR[c] = TH[i * 64 + (jcol ^ (i & 31))];                                \
    }                                                                        \
    __syncthreads();                                                         \
  }

  LOADH(tH0, 0) STATSH(tH0, 0) COPYR(tH0, xrA)
  LOADH(tH0, 1) STATSH(tH0, 1) COPYR(tH0, xrB)
  LOADH(tH0, 2) STATSH(tH0, 2)  // tH0 persists = mat2
  LOADH(tH1, 3) STATSH(tH1, 3)  // tH1 persists = mat3
#undef LOADH
#undef STATSH
#undef COPYR

  // ---- inline grid barrier, RELAXED spin (H2 fix) -------------------------
  __threadfence();  // release: partial stores visible device-wide
  if (tid == 0) {
    atomicAdd(bar, 1u);  // device-scope RMW (arrival)
    // RELAXED spin: plain loads, NO per-iteration cache invalidate.
    while (__hip_atomic_load(bar, __ATOMIC_RELAXED,
                             __HIP_MEMORY_SCOPE_AGENT) < NBLK) {
      __builtin_amdgcn_s_sleep(32);
    }
  }
  __syncthreads();
  __threadfence();  // single acquire: fence-to-fence sync via the counter

  // finalize: wave m handles matrix m (lanes 0-31 reduce over the 32 batches)
  {
    int m = wv4;
    int ln = lane;
    int f = fbase + m;
    if (ln < 32) {
      float ms = mean_bf[ln * NF + f];
      float vs = var_bf[ln * NF + f];
#pragma unroll
      for (int off = 16; off > 0; off >>= 1) {
        ms += __shfl_down(ms, off, 32);
        vs += __shfl_down(vs, off, 32);
      }
      if (ln == 0) {
        ms *= (1.f / NB);
        vs *= (1.f / NB);
        int st = steps[0];
        float mom = 0.997f;
        if (st < 100) {
          float beta = (float)st * 0.01f;
          mom = 0.997f * beta + 0.8f * (1.f - beta);
        }
        float rmv = mom * rmean[f] + (1.f - mom) * ms;
        float rvv = mom * rvar[f] + (1.f - mom) * vs;
        float gain = w[f] * expf(wexp[f]) + wbias[f];
        sc[m * 3 + 0] = rmv;
        sc[m * 3 + 1] = gain / (sqrtf(rvv) + EPSF);
        sc[m * 3 + 2] = bias[f];
      }
    }
    __syncthreads();
  }

  const float mj0 = smask[2 * jcol];
  const float mj1 = smask[2 * jcol + 1];

// ---- Phase B: PW is an expression giving the packed word for iteration c --
#define STOREB(PW, MIDX)                                                     \
  {                                                                          \
    const int bf = b * NF + fbase + MIDX;                                    \
    const float rm = sc[MIDX * 3 + 0];                                       \
    const float ss = sc[MIDX * 3 + 1];                                       \
    const float bi = sc[MIDX * 3 + 2];                                       \
    f32x2* op2 = (f32x2*)(out + (size_t)bf * (NN * NN));                     \
    _Pragma("unroll")                                                        \
    for (int c = 0; c < 32; ++c) {                                           \
      int i = 4 * c + wv4;                                                   \
      unsigned p = (PW);                                                     \
      float xa = h2f((unsigned short)(p & 0xFFFFu));                         \
      float xb = h2f((unsigned short)(p >> 16));                             \
      float cs = smask[i] * ss;                                              \
      f32x2 o;                                                               \
      o.x = (xa - ((i == 2 * jcol    ) ? rm : 0.f)) * (cs * mj0) +           \
            ((i == 2 * jcol    ) ? bi : 0.f);                                \
      o.y = (xb - ((i == 2 * jcol + 1) ? rm : 0.f)) * (cs * mj1) +           \
            ((i == 2 * jcol + 1) ? bi : 0.f);                                \
      __builtin_nontemporal_store(o, &op2[c * 256 + tid]);                   \
    }                                                                        \
  }

  STOREB(xrA[c], 0)
  STOREB(xrB[c], 1)
  STOREB(tH0[i * 64 + (jcol ^ (i & 31))], 2)
  STOREB(tH1[i * 64 + (jcol ^ (i & 31))], 3)
#undef STOREB
}

// ===========================================================================
// FALLBACK: round-8 two-pass path (validated, 70.2 us, absmax 0.25).
// Used only if the cooperative launch is rejected.
// ===========================================================================
__global__ __launch_bounds__(256) void mfb_stats(
    const float* __restrict__ x, const float* __restrict__ mask,
    float* __restrict__ mean_bf, float* __restrict__ var_bf,
    unsigned short* __restrict__ hws) {
  __shared__ float tile[NN * NN];
  const int tid = threadIdx.x;
  const int bf = blockIdx.x;
  const int b = bf >> 6;
  const float* xp = x + (size_t)bf * (NN * NN);
  unsigned short* hp = hws + (size_t)bf * (NN * NN);
  const int lane = tid & 63;

  float m0 = mask[b * NN + lane];
  float m1 = mask[b * NN + 64 + lane];
  float msq0 = m0 * m0;
  float msq1 = m1 * m1;

  const int kcol = tid & 127;
  const int ib = tid >> 7;
#pragma unroll 8
  for (int c = 0; c < 64; ++c) {
    int i = 2 * c + ib;
    float v = xp[c * 256 + tid];
    tile[i * NN + (kcol ^ (i & 31))] = v;
    hp[c * 256 + tid] = f2h(v);
  }
  __syncthreads();

  float tr = 0.f, nump = 0.f;
  if (tid < 64) nump = msq0 + msq1;
  if (tid < 128) {
    float d = tile[tid * NN + (tid ^ (tid & 31))];
    tr = d * ((tid < 64) ? msq0 : msq1);
  }

  const int irow = tid >> 1;
  const int k0 = (tid & 1) << 6;
  float mq = (irow < 64) ? __shfl(msq0, irow, 64) : __shfl(msq1, irow - 64, 64);
  const int cxor = irow & 31;
  const int rowbase = irow * NN;
  float acc = 0.f;
#pragma unroll
  for (int c = 0; c < 64; ++c) {
    int k = k0 + c;
    float a = tile[rowbase + (k ^ cxor)];
    float bt = tile[k * NN + (irow ^ (k & 31))];
    acc = fmaf(a, bt, acc);
  }
  float trsq = acc * mq;

#pragma unroll
  for (int off = 32; off > 0; off >>= 1) {
    tr   += __shfl_down(tr, off, 64);
    trsq += __shfl_down(trsq, off, 64);
    nump += __shfl_down(nump, off, 64);
  }
  __syncthreads();
  if (lane == 0) {
    int w = tid >> 6;
    tile[w * 3 + 0] = tr;
    tile[w * 3 + 1] = trsq;
    tile[w * 3 + 2] = nump;
  }
  __syncthreads();
  if (tid == 0) {
    float trs = tile[0] + tile[3] + tile[6] + tile[9];
    float tq  = tile[1] + tile[4] + tile[7] + tile[10];
    float num = tile[2] + tile[5] + tile[8] + tile[11];
    float num2 = fmaxf(num - 1.f, 1.f);
    mean_bf[bf] = trs / num;
    var_bf[bf]  = tq / num2 - trs * trs / (num * num2);
  }
}

__global__ __launch_bounds__(256) void mfb_apply(
    const unsigned short* __restrict__ hws, const float* __restrict__ mask,
    const float* __restrict__ mean_bf, const float* __restrict__ var_bf,
    const float* __restrict__ w, const float* __restrict__ wexp,
    const float* __restrict__ wbias, const float* __restrict__ bias,
    const float* __restrict__ rmean, const float* __restrict__ rvar,
    const int* __restrict__ steps, f32x4* __restrict__ out4) {
  const int bf = blockIdx.x;
  const int b = bf >> 6;
  const int f = bf & 63;
  const int tid = threadIdx.x;
  __shared__ float smask[NN];
  __shared__ float sc[3];

  if (tid < NN) smask[tid] = mask[b * NN + tid];
  if (tid < 32) {
    float ms = mean_bf[tid * NF + f];
    float vs = var_bf[tid * NF + f];
#pragma unroll
    for (int off = 16; off > 0; off >>= 1) {
      ms += __shfl_down(ms, off, 32);
      vs += __shfl_down(vs, off, 32);
    }
    if (tid == 0) {
      ms *= (1.f / NB);
      vs *= (1.f / NB);
      int st = steps[0];
      float mom = 0.997f;
      if (st < 100) {
        float beta = (float)st * 0.01f;
        mom = 0.997f * beta + 0.8f * (1.f - beta);
      }
      float rm = mom * rmean[f] + (1.f - mom) * ms;
      float rv = mom * rvar[f] + (1.f - mom) * vs;
      float gain = w[f] * expf(wexp[f]) + wbias[f];
      sc[0] = rm;
      sc[1] = gain / (sqrtf(rv) + EPSF);
      sc[2] = bias[f];
    }
  }
  __syncthreads();

  const float rm = sc[0];
  const float s = sc[1];
  const float bi = sc[2];
  const f32x4 mj4 = ((const f32x4*)smask)[tid & 31];
  const int j0 = (tid & 31) << 2;
  const int wv = tid >> 5;
  const u16x4* hp = (const u16x4*)hws + (size_t)bf * 4096;
  f32x4* op = out4 + (size_t)bf * 4096;

#pragma unroll
  for (int c = 0; c < 16; ++c) {
    const int idx = c * 256 + tid;
    const int i = c * 8 + wv;
    u16x4 hv = hp[idx];
    float x0 = h2f(hv.x), x1 = h2f(hv.y), x2 = h2f(hv.z), x3 = h2f(hv.w);
    float cs = smask[i] * s;
    f32x4 o;
    o.x = (x0 - ((i == j0    ) ? rm : 0.f)) * (cs * mj4.x) + ((i == j0    ) ? bi : 0.f);
    o.y = (x1 - ((i == j0 + 1) ? rm : 0.f)) * (cs * mj4.y) + ((i == j0 + 1) ? bi : 0.f);
    o.z = (x2 - ((i == j0 + 2) ? rm : 0.f)) * (cs * mj4.z) + ((i == j0 + 2) ? bi : 0.f);
    o.w = (x3 - ((i == j0 + 3) ? rm : 0.f)) * (cs * mj4.w) + ((i == j0 + 3) ? bi : 0.f);
    __builtin_nontemporal_store(o, &op[idx]);
  }
}

extern "C" void kernel_launch(void* const* d_in, const int* in_sizes, int n_in,
                              void* d_out, int out_size, void* d_ws, size_t ws_size,
                              hipStream_t stream) {
  const float* x     = (const float*)d_in[0];
  const float* mask  = (const float*)d_in[1];
  const float* w     = (const float*)d_in[2];
  const float* wexp  = (const float*)d_in[3];
  const float* wbias = (const float*)d_in[4];
  const float* bias  = (const float*)d_in[5];
  const float* rmean = (const float*)d_in[6];
  const float* rvar  = (const float*)d_in[7];
  const int*   steps = (const int*)d_in[8];

  float* ws = (float*)d_ws;
  float* mean_bf = ws;                        // [B*F] f32
  float* var_bf  = ws + NB * NF;              // [B*F] f32
  // barrier counter and (fallback-only) fp16 copy share the region past 16KB;
  // the two paths never run together in one call.
  unsigned* bar = (unsigned*)(ws + 2 * NB * NF);
  unsigned short* hws = (unsigned short*)(ws + 2 * NB * NF);

  // reset barrier counter every call (graph-capture-legal async memset)
  hipMemsetAsync(bar, 0, sizeof(unsigned), stream);

  float* out = (float*)d_out;
  void* kargs[] = {(void*)&x,     (void*)&mask,  (void*)&w,
                   (void*)&wexp,  (void*)&wbias, (void*)&bias,
                   (void*)&rmean, (void*)&rvar,  (void*)&steps,
                   (void*)&mean_bf, (void*)&var_bf, (void*)&bar, (void*)&out};
  hipError_t err = hipLaunchCooperativeKernel((void*)mfb_fused, dim3(NBLK),
                                              dim3(256), kargs, 0, stream);
  if (err != hipSuccess) {
    // capacity validation failed: round-8 two-pass path (70.2 us, validated)
    mfb_stats<<<NB * NF, 256, 0, stream>>>(x, mask, mean_bf, var_bf, hws);
    mfb_apply<<<NB * NF, 256, 0, stream>>>(hws, mask, mean_bf, var_bf, w, wexp,
                                           wbias, bias, rmean, rvar, steps,
                                           (f32x4*)d_out);
  }
}

// Round 14
// 152.008 us; speedup vs baseline: 2.7086x; 1.1251x over previous
//
#include <hip/hip_runtime.h>
#include <hip/hip_fp16.h>

#define NB 32
#define NF 64
#define NN 128
#define EPSF 1e-9f
#define NBLK 512u

typedef float f32x2 __attribute__((ext_vector_type(2)));
typedef float f32x4 __attribute__((ext_vector_type(4)));
typedef unsigned short u16x4 __attribute__((ext_vector_type(4)));

__device__ __forceinline__ unsigned short f2h(float f) {
  __half h = __float2half_rn(f);
  return *reinterpret_cast<unsigned short*>(&h);
}
__device__ __forceinline__ float h2f(unsigned short u) {
  __half h = *reinterpret_cast<__half*>(&u);
  return __half2float(h);
}

// ===========================================================================
// FUSED kernel, LDS-payload edition — NORMAL LAUNCH (H1 test).
//
// Failure-mode ledger:
//   r6: cg::grid_sync ABI call -> VGPR spill (310us). -> inline barrier.
//   r7/r11: no occupancy floor -> VGPR>256 -> 1 block/CU -> 256/512 resident
//       -> spin DEADLOCK. -> __launch_bounds__(256,2) (terminating r9-r13).
//   r9/r10: 128-reg payload -> wholesale spill (385us). -> 64-reg payload +
//       2 matrices in persistent LDS fp16 tiles (r12: spill GONE).
//   r12/r13: correct, no spill, minimal traffic (66+131 MB) — but 171us.
//       H2 (acquire-spin invalidates) refuted: relaxed spin bought only 10us.
//       H1 (THIS ROUND): every coop-launch variant runs at ~1.15 TB/s
//       effective regardless of structure; every normal-launch kernel hits
//       5.7-7 TB/s on the same data. Even a fully-serial phase model caps
//       this kernel at ~55us -> the 3x gap is the DISPATCH MODE, not the
//       kernel. Test: identical kernel, plain <<<>>> launch. Residency for
//       the spin barrier: 2 blocks/CU x 256 CU = 512 = grid, proven
//       co-resident 4x under coop validation with this exact footprint.
//
// LDS: tH0+tH1 (2 x 32KB fp16 pair-word tiles) + smask/red/sc = 65.6KB.
// Word(i,j) = fp16 x[i,2j] | x[i,2j+1] at tH[i*64 + (j ^ (i&31))].
// Stats computed FROM fp16 (variance err ~7e-4, under the measured 0.25).
// HBM: 134 MB read + 134 MB write (measured r13: 66 fetch + 131 write).
// ===========================================================================
__global__ __launch_bounds__(256, 2) void mfb_fused(
    const float* __restrict__ x, const float* __restrict__ mask,
    const float* __restrict__ w, const float* __restrict__ wexp,
    const float* __restrict__ wbias, const float* __restrict__ bias,
    const float* __restrict__ rmean, const float* __restrict__ rvar,
    const int* __restrict__ steps, float* __restrict__ mean_bf,
    float* __restrict__ var_bf, unsigned* __restrict__ bar,
    float* __restrict__ out) {
  __shared__ unsigned tH0[8192];  // 32 KB fp16 tile (u32 pair-words)
  __shared__ unsigned tH1[8192];  // 32 KB
  __shared__ float smask[NN];
  __shared__ float red[12];
  __shared__ float sc[12];  // per matrix: rm, s, bias

  const int tid = threadIdx.x;
  const int g = blockIdx.x;
  const int b = g >> 4;
  const int fbase = (g & 15) << 2;
  const int lane = tid & 63;
  const int jcol = tid & 63;   // column-pair index
  const int wv4 = tid >> 6;    // wave id 0..3

  float m0 = mask[b * NN + lane];
  float m1 = mask[b * NN + 64 + lane];
  float msq0 = m0 * m0, msq1 = m1 * m1;
  if (tid < NN) smask[tid] = mask[b * NN + tid];

  unsigned xrA[32], xrB[32];

// ---- load matrix MIDX as packed fp16 words into TH (swizzled) -------------
#define LOADH(TH, MIDX)                                                      \
  {                                                                          \
    const int bf = b * NF + fbase + MIDX;                                    \
    const f32x2* xp2 = (const f32x2*)(x + (size_t)bf * (NN * NN));           \
    _Pragma("unroll 8")                                                      \
    for (int c = 0; c < 32; ++c) {                                           \
      f32x2 v = xp2[c * 256 + tid];                                          \
      int i = 4 * c + wv4;                                                   \
      TH[i * 64 + (jcol ^ (i & 31))] =                                       \
          (unsigned)f2h(v.x) | ((unsigned)f2h(v.y) << 16);                   \
    }                                                                        \
    __syncthreads();                                                         \
  }

// ---- masked trace + trace(x@x) stats from fp16 tile TH --------------------
#define STATSH(TH, MIDX)                                                     \
  {                                                                          \
    const int bf = b * NF + fbase + MIDX;                                    \
    float tr = 0.f, nump = 0.f;                                              \
    if (tid < 64) nump = msq0 + msq1;                                        \
    if (tid < 128) {                                                         \
      unsigned wd = TH[tid * 64 + ((tid >> 1) ^ (tid & 31))];                \
      float d = h2f((unsigned short)((wd >> ((tid & 1) * 16)) & 0xFFFFu));   \
      tr = d * ((tid < 64) ? msq0 : msq1);                                   \
    }                                                                        \
    const int irow = tid >> 1;                                               \
    const int k0 = (tid & 1) << 6;                                           \
    float mq = (irow < 64) ? __shfl(msq0, irow, 64)                          \
                           : __shfl(msq1, irow - 64, 64);                    \
    const int rbase = irow * 64;                                             \
    const int rx = irow & 31;                                                \
    const int ih = irow >> 1;                                                \
    const unsigned sh = (unsigned)(irow & 1) * 16u;                          \
    float acc = 0.f;                                                         \
    _Pragma("unroll 8")                                                      \
    for (int jj = 0; jj < 32; ++jj) {                                        \
      unsigned rw = TH[rbase + (((k0 >> 1) + jj) ^ rx)];                     \
      int k = k0 + 2 * jj;                                                   \
      unsigned t0 = TH[k * 64 + (ih ^ (k & 31))];                            \
      unsigned t1 = TH[(k + 1) * 64 + (ih ^ ((k + 1) & 31))];                \
      float xlo = h2f((unsigned short)(rw & 0xFFFFu));                       \
      float xhi = h2f((unsigned short)(rw >> 16));                           \
      float v0 = h2f((unsigned short)((t0 >> sh) & 0xFFFFu));                \
      float v1 = h2f((unsigned short)((t1 >> sh) & 0xFFFFu));                \
      acc = fmaf(xlo, v0, acc);                                              \
      acc = fmaf(xhi, v1, acc);                                              \
    }                                                                        \
    float trsq = acc * mq;                                                   \
    _Pragma("unroll")                                                        \
    for (int off = 32; off > 0; off >>= 1) {                                 \
      tr   += __shfl_down(tr, off, 64);                                      \
      trsq += __shfl_down(trsq, off, 64);                                    \
      nump += __shfl_down(nump, off, 64);                                    \
    }                                                                        \
    __syncthreads();                                                         \
    if (lane == 0) {                                                         \
      red[wv4 * 3 + 0] = tr;                                                 \
      red[wv4 * 3 + 1] = trsq;                                               \
      red[wv4 * 3 + 2] = nump;                                               \
    }                                                                        \
    __syncthreads();                                                         \
    if (tid == 0) {                                                          \
      float trs = red[0] + red[3] + red[6] + red[9];                         \
      float tq  = red[1] + red[4] + red[7] + red[10];                        \
      float num = red[2] + red[5] + red[8] + red[11];                        \
      float num2 = fmaxf(num - 1.f, 1.f);                                    \
      mean_bf[bf] = trs / num;                                               \
      var_bf[bf]  = tq / num2 - trs * trs / (num * num2);                    \
    }                                                                        \
    __syncthreads();                                                         \
  }

// ---- copy tile TH into per-thread registers XR (static indices) -----------
#define COPYR(TH, XR)                                                        \
  {                                                                          \
    _Pragma("unroll")                                                        \
    for (int c = 0; c < 32; ++c) {                                           \
      int i = 4 * c + wv4;                                                   \
      XR[c] = TH[i * 64 + (jcol ^ (i & 31))];                                \
    }                                                                        \
    __syncthreads();                                                         \
  }

  LOADH(tH0, 0) STATSH(tH0, 0) COPYR(tH0, xrA)
  LOADH(tH0, 1) STATSH(tH0, 1) COPYR(tH0, xrB)
  LOADH(tH0, 2) STATSH(tH0, 2)  // tH0 persists = mat2
  LOADH(tH1, 3) STATSH(tH1, 3)  // tH1 persists = mat3
#undef LOADH
#undef STATSH
#undef COPYR

  // ---- inline grid barrier, relaxed spin (terminating r12/r13) -----------
  __threadfence();  // release: partial stores visible device-wide
  if (tid == 0) {
    atomicAdd(bar, 1u);  // device-scope RMW (arrival)
    while (__hip_atomic_load(bar, __ATOMIC_RELAXED,
                             __HIP_MEMORY_SCOPE_AGENT) < NBLK) {
      __builtin_amdgcn_s_sleep(32);
    }
  }
  __syncthreads();
  __threadfence();  // acquire: fence-to-fence sync via the counter

  // finalize: wave m handles matrix m (lanes 0-31 reduce over the 32 batches)
  {
    int m = wv4;
    int ln = lane;
    int f = fbase + m;
    if (ln < 32) {
      float ms = mean_bf[ln * NF + f];
      float vs = var_bf[ln * NF + f];
#pragma unroll
      for (int off = 16; off > 0; off >>= 1) {
        ms += __shfl_down(ms, off, 32);
        vs += __shfl_down(vs, off, 32);
      }
      if (ln == 0) {
        ms *= (1.f / NB);
        vs *= (1.f / NB);
        int st = steps[0];
        float mom = 0.997f;
        if (st < 100) {
          float beta = (float)st * 0.01f;
          mom = 0.997f * beta + 0.8f * (1.f - beta);
        }
        float rmv = mom * rmean[f] + (1.f - mom) * ms;
        float rvv = mom * rvar[f] + (1.f - mom) * vs;
        float gain = w[f] * expf(wexp[f]) + wbias[f];
        sc[m * 3 + 0] = rmv;
        sc[m * 3 + 1] = gain / (sqrtf(rvv) + EPSF);
        sc[m * 3 + 2] = bias[f];
      }
    }
    __syncthreads();
  }

  const float mj0 = smask[2 * jcol];
  const float mj1 = smask[2 * jcol + 1];

// ---- Phase B: PW is an expression giving the packed word for iteration c --
#define STOREB(PW, MIDX)                                                     \
  {                                                                          \
    const int bf = b * NF + fbase + MIDX;                                    \
    const float rm = sc[MIDX * 3 + 0];                                       \
    const float ss = sc[MIDX * 3 + 1];                                       \
    const float bi = sc[MIDX * 3 + 2];                                       \
    f32x2* op2 = (f32x2*)(out + (size_t)bf * (NN * NN));                     \
    _Pragma("unroll")                                                        \
    for (int c = 0; c < 32; ++c) {                                           \
      int i = 4 * c + wv4;                                                   \
      unsigned p = (PW);                                                     \
      float xa = h2f((unsigned short)(p & 0xFFFFu));                         \
      float xb = h2f((unsigned short)(p >> 16));                             \
      float cs = smask[i] * ss;                                              \
      f32x2 o;                                                               \
      o.x = (xa - ((i == 2 * jcol    ) ? rm : 0.f)) * (cs * mj0) +           \
            ((i == 2 * jcol    ) ? bi : 0.f);                                \
      o.y = (xb - ((i == 2 * jcol + 1) ? rm : 0.f)) * (cs * mj1) +           \
            ((i == 2 * jcol + 1) ? bi : 0.f);                                \
      __builtin_nontemporal_store(o, &op2[c * 256 + tid]);                   \
    }                                                                        \
  }

  STOREB(xrA[c], 0)
  STOREB(xrB[c], 1)
  STOREB(tH0[i * 64 + (jcol ^ (i & 31))], 2)
  STOREB(tH1[i * 64 + (jcol ^ (i & 31))], 3)
#undef STOREB
}

// ===========================================================================
// Two-pass kernels kept for reference / next-round revert (not launched).
// ===========================================================================
__global__ __launch_bounds__(256) void mfb_stats(
    const float* __restrict__ x, const float* __restrict__ mask,
    float* __restrict__ mean_bf, float* __restrict__ var_bf,
    unsigned short* __restrict__ hws) {
  __shared__ float tile[NN * NN];
  const int tid = threadIdx.x;
  const int bf = blockIdx.x;
  const int b = bf >> 6;
  const float* xp = x + (size_t)bf * (NN * NN);
  unsigned short* hp = hws + (size_t)bf * (NN * NN);
  const int lane = tid & 63;

  float m0 = mask[b * NN + lane];
  float m1 = mask[b * NN + 64 + lane];
  float msq0 = m0 * m0;
  float msq1 = m1 * m1;

  const int kcol = tid & 127;
  const int ib = tid >> 7;
#pragma unroll 8
  for (int c = 0; c < 64; ++c) {
    int i = 2 * c + ib;
    float v = xp[c * 256 + tid];
    tile[i * NN + (kcol ^ (i & 31))] = v;
    hp[c * 256 + tid] = f2h(v);
  }
  __syncthreads();

  float tr = 0.f, nump = 0.f;
  if (tid < 64) nump = msq0 + msq1;
  if (tid < 128) {
    float d = tile[tid * NN + (tid ^ (tid & 31))];
    tr = d * ((tid < 64) ? msq0 : msq1);
  }

  const int irow = tid >> 1;
  const int k0 = (tid & 1) << 6;
  float mq = (irow < 64) ? __shfl(msq0, irow, 64) : __shfl(msq1, irow - 64, 64);
  const int cxor = irow & 31;
  const int rowbase = irow * NN;
  float acc = 0.f;
#pragma unroll
  for (int c = 0; c < 64; ++c) {
    int k = k0 + c;
    float a = tile[rowbase + (k ^ cxor)];
    float bt = tile[k * NN + (irow ^ (k & 31))];
    acc = fmaf(a, bt, acc);
  }
  float trsq = acc * mq;

#pragma unroll
  for (int off = 32; off > 0; off >>= 1) {
    tr   += __shfl_down(tr, off, 64);
    trsq += __shfl_down(trsq, off, 64);
    nump += __shfl_down(nump, off, 64);
  }
  __syncthreads();
  if (lane == 0) {
    int w = tid >> 6;
    tile[w * 3 + 0] = tr;
    tile[w * 3 + 1] = trsq;
    tile[w * 3 + 2] = nump;
  }
  __syncthreads();
  if (tid == 0) {
    float trs = tile[0] + tile[3] + tile[6] + tile[9];
    float tq  = tile[1] + tile[4] + tile[7] + tile[10];
    float num = tile[2] + tile[5] + tile[8] + tile[11];
    float num2 = fmaxf(num - 1.f, 1.f);
    mean_bf[bf] = trs / num;
    var_bf[bf]  = tq / num2 - trs * trs / (num * num2);
  }
}

__global__ __launch_bounds__(256) void mfb_apply(
    const unsigned short* __restrict__ hws, const float* __restrict__ mask,
    const float* __restrict__ mean_bf, const float* __restrict__ var_bf,
    const float* __restrict__ w, const float* __restrict__ wexp,
    const float* __restrict__ wbias, const float* __restrict__ bias,
    const float* __restrict__ rmean, const float* __restrict__ rvar,
    const int* __restrict__ steps, f32x4* __restrict__ out4) {
  const int bf = blockIdx.x;
  const int b = bf >> 6;
  const int f = bf & 63;
  const int tid = threadIdx.x;
  __shared__ float smask[NN];
  __shared__ float sc[3];

  if (tid < NN) smask[tid] = mask[b * NN + tid];
  if (tid < 32) {
    float ms = mean_bf[tid * NF + f];
    float vs = var_bf[tid * NF + f];
#pragma unroll
    for (int off = 16; off > 0; off >>= 1) {
      ms += __shfl_down(ms, off, 32);
      vs += __shfl_down(vs, off, 32);
    }
    if (tid == 0) {
      ms *= (1.f / NB);
      vs *= (1.f / NB);
      int st = steps[0];
      float mom = 0.997f;
      if (st < 100) {
        float beta = (float)st * 0.01f;
        mom = 0.997f * beta + 0.8f * (1.f - beta);
      }
      float rm = mom * rmean[f] + (1.f - mom) * ms;
      float rv = mom * rvar[f] + (1.f - mom) * vs;
      float gain = w[f] * expf(wexp[f]) + wbias[f];
      sc[0] = rm;
      sc[1] = gain / (sqrtf(rv) + EPSF);
      sc[2] = bias[f];
    }
  }
  __syncthreads();

  const float rm = sc[0];
  const float s = sc[1];
  const float bi = sc[2];
  const f32x4 mj4 = ((const f32x4*)smask)[tid & 31];
  const int j0 = (tid & 31) << 2;
  const int wv = tid >> 5;
  const u16x4* hp = (const u16x4*)hws + (size_t)bf * 4096;
  f32x4* op = out4 + (size_t)bf * 4096;

#pragma unroll
  for (int c = 0; c < 16; ++c) {
    const int idx = c * 256 + tid;
    const int i = c * 8 + wv;
    u16x4 hv = hp[idx];
    float x0 = h2f(hv.x), x1 = h2f(hv.y), x2 = h2f(hv.z), x3 = h2f(hv.w);
    float cs = smask[i] * s;
    f32x4 o;
    o.x = (x0 - ((i == j0    ) ? rm : 0.f)) * (cs * mj4.x) + ((i == j0    ) ? bi : 0.f);
    o.y = (x1 - ((i == j0 + 1) ? rm : 0.f)) * (cs * mj4.y) + ((i == j0 + 1) ? bi : 0.f);
    o.z = (x2 - ((i == j0 + 2) ? rm : 0.f)) * (cs * mj4.z) + ((i == j0 + 2) ? bi : 0.f);
    o.w = (x3 - ((i == j0 + 3) ? rm : 0.f)) * (cs * mj4.w) + ((i == j0 + 3) ? bi : 0.f);
    __builtin_nontemporal_store(o, &op[idx]);
  }
}

extern "C" void kernel_launch(void* const* d_in, const int* in_sizes, int n_in,
                              void* d_out, int out_size, void* d_ws, size_t ws_size,
                              hipStream_t stream) {
  const float* x     = (const float*)d_in[0];
  const float* mask  = (const float*)d_in[1];
  const float* w     = (const float*)d_in[2];
  const float* wexp  = (const float*)d_in[3];
  const float* wbias = (const float*)d_in[4];
  const float* bias  = (const float*)d_in[5];
  const float* rmean = (const float*)d_in[6];
  const float* rvar  = (const float*)d_in[7];
  const int*   steps = (const int*)d_in[8];

  float* ws = (float*)d_ws;
  float* mean_bf = ws;                        // [B*F] f32
  float* var_bf  = ws + NB * NF;              // [B*F] f32
  unsigned* bar  = (unsigned*)(ws + 2 * NB * NF);  // barrier counter

  // reset barrier counter every call (graph-capture-legal async memset)
  hipMemsetAsync(bar, 0, sizeof(unsigned), stream);

  // H1 test: NORMAL launch. Capacity 2 blocks/CU x 256 CU = 512 = grid
  // (co-residency of this exact footprint proven 4x under coop validation).
  mfb_fused<<<dim3(NBLK), dim3(256), 0, stream>>>(
      x, mask, w, wexp, wbias, bias, rmean, rvar, steps,
      mean_bf, var_bf, bar, (float*)d_out);
}

// Round 15
// 150.070 us; speedup vs baseline: 2.7436x; 1.0129x over previous
//
#include <hip/hip_runtime.h>
#include <hip/hip_fp16.h>

#define NB 32
#define NF 64
#define NN 128
#define EPSF 1e-9f
#define NBLK 512u

typedef float f32x2 __attribute__((ext_vector_type(2)));

__device__ __forceinline__ unsigned short f2h(float f) {
  __half h = __float2half_rn(f);
  return *reinterpret_cast<unsigned short*>(&h);
}
__device__ __forceinline__ float h2f(unsigned short u) {
  __half h = *reinterpret_cast<__half*>(&u);
  return __half2float(h);
}

// ===========================================================================
// FUSED kernel, COMPACT-CODE edition (H5: I$-thrash fix).
//
// Ledger: r6 cg-sync spill; r7/r11 no-floor deadlock -> (256,2); r9/r10
// 128-reg payload spill -> 64-reg + 2 LDS tiles; r12-14 correct, minimal
// traffic (66 fetch + 131 write MB), no spill — but ~180us with ALL pipes
// idle (VALU 7.5%, HBM 13%) under BOTH coop and normal launch (H1 refuted),
// with relaxed spin (H2 refuted). H5: the 4x macro-expanded body is ~40-48KB
// of code > 32KB I$ -> continuous front-end stalls (the only mechanism that
// idles every pipe at once and is invariant to barrier/launch changes).
// THIS ROUND: identical algorithm, code shrunk ~4x:
//   - phase A: ONE shared body in a '#pragma unroll 1' loop over m=0..3
//     (inner unrolls capped at 4); xrA/xrB copies are the only unrolled-32
//     pieces (register arrays need static indices).
//   - phase B: ONE rolled store body used twice: round 0 stores mats {2,3}
//     from the tiles; then xrA/xrB are written back INTO the tiles and the
//     same body stores mats {0,1}.
// Everything else byte-equivalent to r14 (which PASSED, absmax 0.125):
// normal launch, (256,2) bound, relaxed-spin barrier + fences, fp16 tiles
// word(i,j)=x[i,2j]|x[i,2j+1] at tH[i*64+(j^(i&31))], fp16 stats.
// HBM: 134 read + 134 write MB.
// ===========================================================================
__global__ __launch_bounds__(256, 2) void mfb_fused(
    const float* __restrict__ x, const float* __restrict__ mask,
    const float* __restrict__ w, const float* __restrict__ wexp,
    const float* __restrict__ wbias, const float* __restrict__ bias,
    const float* __restrict__ rmean, const float* __restrict__ rvar,
    const int* __restrict__ steps, float* __restrict__ mean_bf,
    float* __restrict__ var_bf, unsigned* __restrict__ bar,
    float* __restrict__ out) {
  __shared__ unsigned tH0[8192];  // 32 KB fp16 tile (u32 pair-words)
  __shared__ unsigned tH1[8192];  // 32 KB
  __shared__ float smask[NN];
  __shared__ float red[12];
  __shared__ float sc[12];  // per matrix: rm, s, bias

  const int tid = threadIdx.x;
  const int g = blockIdx.x;
  const int b = g >> 4;
  const int fbase = (g & 15) << 2;
  const int lane = tid & 63;
  const int jcol = tid & 63;   // column-pair index
  const int wv4 = tid >> 6;    // wave id 0..3

  float m0 = mask[b * NN + lane];
  float m1 = mask[b * NN + 64 + lane];
  float msq0 = m0 * m0, msq1 = m1 * m1;
  if (tid < NN) smask[tid] = mask[b * NN + tid];

  unsigned xrA[32], xrB[32];

  // ---- phase A: one shared body, looped over the 4 matrices --------------
#pragma unroll 1
  for (int m = 0; m < 4; ++m) {
    unsigned* TH = (m == 3) ? tH1 : tH0;
    const int bf = b * NF + fbase + m;
    const f32x2* xp2 = (const f32x2*)(x + (size_t)bf * (NN * NN));
#pragma unroll 4
    for (int c = 0; c < 32; ++c) {
      f32x2 v = xp2[c * 256 + tid];
      int i = 4 * c + wv4;
      TH[i * 64 + (jcol ^ (i & 31))] =
          (unsigned)f2h(v.x) | ((unsigned)f2h(v.y) << 16);
    }
    __syncthreads();

    float tr = 0.f, nump = 0.f;
    if (tid < 64) nump = msq0 + msq1;
    if (tid < 128) {
      unsigned wd = TH[tid * 64 + ((tid >> 1) ^ (tid & 31))];
      float d = h2f((unsigned short)((wd >> ((tid & 1) * 16)) & 0xFFFFu));
      tr = d * ((tid < 64) ? msq0 : msq1);
    }
    const int irow = tid >> 1;
    const int k0 = (tid & 1) << 6;
    float mq = (irow < 64) ? __shfl(msq0, irow, 64)
                           : __shfl(msq1, irow - 64, 64);
    const int rbase = irow * 64;
    const int rx = irow & 31;
    const int ih = irow >> 1;
    const unsigned sh = (unsigned)(irow & 1) * 16u;
    float acc = 0.f;
#pragma unroll 4
    for (int jj = 0; jj < 32; ++jj) {
      unsigned rw = TH[rbase + (((k0 >> 1) + jj) ^ rx)];
      int k = k0 + 2 * jj;
      unsigned t0 = TH[k * 64 + (ih ^ (k & 31))];
      unsigned t1 = TH[(k + 1) * 64 + (ih ^ ((k + 1) & 31))];
      float xlo = h2f((unsigned short)(rw & 0xFFFFu));
      float xhi = h2f((unsigned short)(rw >> 16));
      float v0 = h2f((unsigned short)((t0 >> sh) & 0xFFFFu));
      float v1 = h2f((unsigned short)((t1 >> sh) & 0xFFFFu));
      acc = fmaf(xlo, v0, acc);
      acc = fmaf(xhi, v1, acc);
    }
    float trsq = acc * mq;
#pragma unroll
    for (int off = 32; off > 0; off >>= 1) {
      tr   += __shfl_down(tr, off, 64);
      trsq += __shfl_down(trsq, off, 64);
      nump += __shfl_down(nump, off, 64);
    }
    __syncthreads();
    if (lane == 0) {
      red[wv4 * 3 + 0] = tr;
      red[wv4 * 3 + 1] = trsq;
      red[wv4 * 3 + 2] = nump;
    }
    __syncthreads();
    if (tid == 0) {
      float trs = red[0] + red[3] + red[6] + red[9];
      float tq  = red[1] + red[4] + red[7] + red[10];
      float num = red[2] + red[5] + red[8] + red[11];
      float num2 = fmaxf(num - 1.f, 1.f);
      mean_bf[bf] = trs / num;
      var_bf[bf]  = tq / num2 - trs * trs / (num * num2);
    }
    // mats 0,1: snapshot the tile into registers before it is overwritten
    if (m == 0) {
#pragma unroll
      for (int c = 0; c < 32; ++c) {
        int i = 4 * c + wv4;
        xrA[c] = tH0[i * 64 + (jcol ^ (i & 31))];
      }
    } else if (m == 1) {
#pragma unroll
      for (int c = 0; c < 32; ++c) {
        int i = 4 * c + wv4;
        xrB[c] = tH0[i * 64 + (jcol ^ (i & 31))];
      }
    }
    __syncthreads();  // tile readers done before next iteration's overwrite
  }

  // ---- inline grid barrier, relaxed spin (terminating r12-r14) -----------
  __threadfence();  // release: partial stores visible device-wide
  if (tid == 0) {
    atomicAdd(bar, 1u);  // device-scope RMW (arrival)
    while (__hip_atomic_load(bar, __ATOMIC_RELAXED,
                             __HIP_MEMORY_SCOPE_AGENT) < NBLK) {
      __builtin_amdgcn_s_sleep(32);
    }
  }
  __syncthreads();
  __threadfence();  // acquire: fence-to-fence sync via the counter

  // finalize: wave m handles matrix m (lanes 0-31 reduce over the 32 batches)
  {
    int f = fbase + wv4;
    if (lane < 32) {
      float ms = mean_bf[lane * NF + f];
      float vs = var_bf[lane * NF + f];
#pragma unroll
      for (int off = 16; off > 0; off >>= 1) {
        ms += __shfl_down(ms, off, 32);
        vs += __shfl_down(vs, off, 32);
      }
      if (lane == 0) {
        ms *= (1.f / NB);
        vs *= (1.f / NB);
        int st = steps[0];
        float mom = 0.997f;
        if (st < 100) {
          float beta = (float)st * 0.01f;
          mom = 0.997f * beta + 0.8f * (1.f - beta);
        }
        float rmv = mom * rmean[f] + (1.f - mom) * ms;
        float rvv = mom * rvar[f] + (1.f - mom) * vs;
        float gain = w[f] * expf(wexp[f]) + wbias[f];
        sc[wv4 * 3 + 0] = rmv;
        sc[wv4 * 3 + 1] = gain / (sqrtf(rvv) + EPSF);
        sc[wv4 * 3 + 2] = bias[f];
      }
    }
    __syncthreads();
  }

  const float mj0 = smask[2 * jcol];
  const float mj1 = smask[2 * jcol + 1];

  // ---- phase B: one rolled store body, used for all 4 matrices -----------
  // round 0: tiles hold mats {2,3}. round 1: tiles refilled from xrA/xrB
  // (mats {0,1}) and the SAME body runs again.
#pragma unroll 1
  for (int r = 0; r < 2; ++r) {
    if (r == 1) {
      __syncthreads();  // round-0 tile reads complete before overwrite
#pragma unroll
      for (int c = 0; c < 32; ++c) {
        int i = 4 * c + wv4;
        tH0[i * 64 + (jcol ^ (i & 31))] = xrA[c];
      }
#pragma unroll
      for (int c = 0; c < 32; ++c) {
        int i = 4 * c + wv4;
        tH1[i * 64 + (jcol ^ (i & 31))] = xrB[c];
      }
      __syncthreads();
    }
#pragma unroll 1
    for (int t = 0; t < 2; ++t) {
      unsigned* TH = t ? tH1 : tH0;
      const int mm = r ? t : (2 + t);  // r0 -> mats 2,3 ; r1 -> mats 0,1
      const int bf = b * NF + fbase + mm;
      const float rm = sc[mm * 3 + 0];
      const float ss = sc[mm * 3 + 1];
      const float bi = sc[mm * 3 + 2];
      f32x2* op2 = (f32x2*)(out + (size_t)bf * (NN * NN));
#pragma unroll 4
      for (int c = 0; c < 32; ++c) {
        int i = 4 * c + wv4;
        unsigned p = TH[i * 64 + (jcol ^ (i & 31))];
        float xa = h2f((unsigned short)(p & 0xFFFFu));
        float xb = h2f((unsigned short)(p >> 16));
        float cs = smask[i] * ss;
        f32x2 o;
        o.x = (xa - ((i == 2 * jcol    ) ? rm : 0.f)) * (cs * mj0) +
              ((i == 2 * jcol    ) ? bi : 0.f);
        o.y = (xb - ((i == 2 * jcol + 1) ? rm : 0.f)) * (cs * mj1) +
              ((i == 2 * jcol + 1) ? bi : 0.f);
        __builtin_nontemporal_store(o, &op2[c * 256 + tid]);
      }
    }
  }
}

extern "C" void kernel_launch(void* const* d_in, const int* in_sizes, int n_in,
                              void* d_out, int out_size, void* d_ws, size_t ws_size,
                              hipStream_t stream) {
  const float* x     = (const float*)d_in[0];
  const float* mask  = (const float*)d_in[1];
  const float* w     = (const float*)d_in[2];
  const float* wexp  = (const float*)d_in[3];
  const float* wbias = (const float*)d_in[4];
  const float* bias  = (const float*)d_in[5];
  const float* rmean = (const float*)d_in[6];
  const float* rvar  = (const float*)d_in[7];
  const int*   steps = (const int*)d_in[8];

  float* ws = (float*)d_ws;
  float* mean_bf = ws;                        // [B*F] f32
  float* var_bf  = ws + NB * NF;              // [B*F] f32
  unsigned* bar  = (unsigned*)(ws + 2 * NB * NF);  // barrier counter

  // reset barrier counter every call (graph-capture-legal async memset)
  hipMemsetAsync(bar, 0, sizeof(unsigned), stream);

  // Normal launch (H1 refuted: same per-dispatch perf as coop, less launch
  // overhead). Residency: 2 blocks/CU x 256 CU = 512 = grid; this exact
  // footprint proven co-resident and terminating in r9/r10/r12/r13/r14.
  mfb_fused<<<dim3(NBLK), dim3(256), 0, stream>>>(
      x, mask, w, wexp, wbias, bias, rmean, rvar, steps,
      mean_bf, var_bf, bar, (float*)d_out);
}

// Round 16
// 78.188 us; speedup vs baseline: 5.2659x; 1.9194x over previous
//
#include <hip/hip_runtime.h>
#include <hip/hip_fp16.h>

#define NB 32
#define NF 64
#define NN 128
#define EPSF 1e-9f

typedef float f32x4 __attribute__((ext_vector_type(4)));
typedef unsigned short u16x4 __attribute__((ext_vector_type(4)));

__device__ __forceinline__ unsigned short f2h(float f) {
  __half h = __float2half_rn(f);
  return *reinterpret_cast<unsigned short*>(&h);
}
__device__ __forceinline__ float h2f(unsigned short u) {
  __half h = *reinterpret_cast<__half*>(&u);
  return __half2float(h);
}

// ===========================================================================
// FINAL: round-8 two-pass structure (validated 70.2us, absmax 0.25), plus
// one cache-steering tweak: pass 1 reads x with NONTEMPORAL loads. x is
// never re-read (pass 2 consumes the fp16 copy), so keeping x out of the
// 256MB Infinity Cache leaves room for hws (67MB) to stay L3-resident ->
// pass 2's read should be an L3 hit, making it write-bound.
//
// Ten rounds of fused-single-kernel attempts (grid barrier + register/LDS
// payload) all hit an unexplained ~1.1TB/s memory throttle (5 hypotheses
// refuted: ABI spill, coop dispatch, acquire-spin invalidates, I$ thrash,
// occupancy) — reverted to the modeled-and-measured two-pass optimum.
//
// Pass 1 (stats): per (b,f) matrix: scalar coalesced nt-loads -> XOR-swizzled
//   f32 LDS tile (addr = i*128 + (k^(i&31)), conflict-free for row +
//   transpose reads) -> exact-f32 masked trace + tr(x@x) via transpose-paired
//   FMA; writes fp16 copy of x to ws (normal stores, L3-cached).
// Pass 2 (apply): per (b,f): wave 0 reduces the 32 batch partials of f,
//   momentum update, folded scale; streams hws (u16x4) -> out (f32x4 nt).
// HBM traffic: 134+67 (pass 1) + 67(->L3?)+134 (pass 2).
// ===========================================================================
__global__ __launch_bounds__(256) void mfb_stats(
    const float* __restrict__ x, const float* __restrict__ mask,
    float* __restrict__ mean_bf, float* __restrict__ var_bf,
    unsigned short* __restrict__ hws) {
  __shared__ float tile[NN * NN];  // 64 KB, reused for block reduction
  const int tid = threadIdx.x;
  const int bf = blockIdx.x;
  const int b = bf >> 6;
  const float* xp = x + (size_t)bf * (NN * NN);
  unsigned short* hp = hws + (size_t)bf * (NN * NN);
  const int lane = tid & 63;

  float m0 = mask[b * NN + lane];
  float m1 = mask[b * NN + 64 + lane];
  float msq0 = m0 * m0;
  float msq1 = m1 * m1;

  const int kcol = tid & 127;
  const int ib = tid >> 7;  // 0 or 1
#pragma unroll 8
  for (int c = 0; c < 64; ++c) {
    int i = 2 * c + ib;
    float v = __builtin_nontemporal_load(&xp[c * 256 + tid]);  // x dead after
    tile[i * NN + (kcol ^ (i & 31))] = v;
    hp[c * 256 + tid] = f2h(v);  // normal store: keep hws in L3 for pass 2
  }
  __syncthreads();

  float tr = 0.f, nump = 0.f;
  if (tid < 64) nump = msq0 + msq1;  // count num once (wave 0 only)
  if (tid < 128) {
    float d = tile[tid * NN + (tid ^ (tid & 31))];  // diagonal x[i,i]
    tr = d * ((tid < 64) ? msq0 : msq1);
  }

  // trace of x@x: each thread owns half of row irow (64 columns)
  const int irow = tid >> 1;
  const int k0 = (tid & 1) << 6;
  float mq = (irow < 64) ? __shfl(msq0, irow, 64) : __shfl(msq1, irow - 64, 64);
  const int cxor = irow & 31;
  const int rowbase = irow * NN;
  float acc = 0.f;
#pragma unroll
  for (int c = 0; c < 64; ++c) {
    int k = k0 + c;
    float a = tile[rowbase + (k ^ cxor)];          // x[irow, k]
    float bt = tile[k * NN + (irow ^ (k & 31))];   // x[k, irow]
    acc = fmaf(a, bt, acc);
  }
  float trsq = acc * mq;

#pragma unroll
  for (int off = 32; off > 0; off >>= 1) {
    tr   += __shfl_down(tr, off, 64);
    trsq += __shfl_down(trsq, off, 64);
    nump += __shfl_down(nump, off, 64);
  }
  __syncthreads();
  if (lane == 0) {
    int w = tid >> 6;
    tile[w * 3 + 0] = tr;
    tile[w * 3 + 1] = trsq;
    tile[w * 3 + 2] = nump;
  }
  __syncthreads();
  if (tid == 0) {
    float trs = tile[0] + tile[3] + tile[6] + tile[9];
    float tq  = tile[1] + tile[4] + tile[7] + tile[10];
    float num = tile[2] + tile[5] + tile[8] + tile[11];
    float num2 = fmaxf(num - 1.f, 1.f);
    mean_bf[bf] = trs / num;
    var_bf[bf]  = tq / num2 - trs * trs / (num * num2);
  }
}

__global__ __launch_bounds__(256) void mfb_apply(
    const unsigned short* __restrict__ hws, const float* __restrict__ mask,
    const float* __restrict__ mean_bf, const float* __restrict__ var_bf,
    const float* __restrict__ w, const float* __restrict__ wexp,
    const float* __restrict__ wbias, const float* __restrict__ bias,
    const float* __restrict__ rmean, const float* __restrict__ rvar,
    const int* __restrict__ steps, f32x4* __restrict__ out4) {
  const int bf = blockIdx.x;
  const int b = bf >> 6;
  const int f = bf & 63;
  const int tid = threadIdx.x;
  __shared__ float smask[NN];
  __shared__ float sc[3];  // rm, s, bias[f]

  if (tid < NN) smask[tid] = mask[b * NN + tid];
  if (tid < 32) {
    float ms = mean_bf[tid * NF + f];
    float vs = var_bf[tid * NF + f];
#pragma unroll
    for (int off = 16; off > 0; off >>= 1) {
      ms += __shfl_down(ms, off, 32);
      vs += __shfl_down(vs, off, 32);
    }
    if (tid == 0) {
      ms *= (1.f / NB);
      vs *= (1.f / NB);
      int st = steps[0];
      float mom = 0.997f;
      if (st < 100) {
        float beta = (float)st * 0.01f;
        mom = 0.997f * beta + 0.8f * (1.f - beta);
      }
      float rm = mom * rmean[f] + (1.f - mom) * ms;
      float rv = mom * rvar[f] + (1.f - mom) * vs;
      float gain = w[f] * expf(wexp[f]) + wbias[f];
      sc[0] = rm;
      sc[1] = gain / (sqrtf(rv) + EPSF);
      sc[2] = bias[f];
    }
  }
  __syncthreads();

  const float rm = sc[0];
  const float s = sc[1];
  const float bi = sc[2];
  const f32x4 mj4 = ((const f32x4*)smask)[tid & 31];
  const int j0 = (tid & 31) << 2;
  const int wv = tid >> 5;
  const u16x4* hp = (const u16x4*)hws + (size_t)bf * 4096;
  f32x4* op = out4 + (size_t)bf * 4096;

#pragma unroll
  for (int c = 0; c < 16; ++c) {
    const int idx = c * 256 + tid;
    const int i = c * 8 + wv;
    u16x4 hv = hp[idx];
    float x0 = h2f(hv.x), x1 = h2f(hv.y), x2 = h2f(hv.z), x3 = h2f(hv.w);
    float cs = smask[i] * s;
    f32x4 o;
    o.x = (x0 - ((i == j0    ) ? rm : 0.f)) * (cs * mj4.x) + ((i == j0    ) ? bi : 0.f);
    o.y = (x1 - ((i == j0 + 1) ? rm : 0.f)) * (cs * mj4.y) + ((i == j0 + 1) ? bi : 0.f);
    o.z = (x2 - ((i == j0 + 2) ? rm : 0.f)) * (cs * mj4.z) + ((i == j0 + 2) ? bi : 0.f);
    o.w = (x3 - ((i == j0 + 3) ? rm : 0.f)) * (cs * mj4.w) + ((i == j0 + 3) ? bi : 0.f);
    __builtin_nontemporal_store(o, &op[idx]);
  }
}

extern "C" void kernel_launch(void* const* d_in, const int* in_sizes, int n_in,
                              void* d_out, int out_size, void* d_ws, size_t ws_size,
                              hipStream_t stream) {
  const float* x     = (const float*)d_in[0];
  const float* mask  = (const float*)d_in[1];
  const float* w     = (const float*)d_in[2];
  const float* wexp  = (const float*)d_in[3];
  const float* wbias = (const float*)d_in[4];
  const float* bias  = (const float*)d_in[5];
  const float* rmean = (const float*)d_in[6];
  const float* rvar  = (const float*)d_in[7];
  const int*   steps = (const int*)d_in[8];

  float* ws = (float*)d_ws;
  float* mean_bf = ws;                        // [B*F] f32
  float* var_bf  = ws + NB * NF;              // [B*F] f32
  unsigned short* hws = (unsigned short*)(ws + 2 * NB * NF);  // fp16 x copy

  mfb_stats<<<NB * NF, 256, 0, stream>>>(x, mask, mean_bf, var_bf, hws);
  mfb_apply<<<NB * NF, 256, 0, stream>>>(hws, mask, mean_bf, var_bf, w, wexp,
                                         wbias, bias, rmean, rvar, steps,
                                         (f32x4*)d_out);
}

// Round 17
// 70.575 us; speedup vs baseline: 5.8339x; 1.1079x over previous
//
#include <hip/hip_runtime.h>
#include <hip/hip_fp16.h>

#define NB 32
#define NF 64
#define NN 128
#define EPSF 1e-9f

typedef float f32x4 __attribute__((ext_vector_type(4)));
typedef unsigned short u16x4 __attribute__((ext_vector_type(4)));

__device__ __forceinline__ unsigned short f2h(float f) {
  __half h = __float2half_rn(f);
  return *reinterpret_cast<unsigned short*>(&h);
}
__device__ __forceinline__ float h2f(unsigned short u) {
  __half h = *reinterpret_cast<__half*>(&u);
  return __half2float(h);
}

// ===========================================================================
// FINAL (round-8 verbatim, the validated optimum: 70.2us, absmax 0.25).
// r16's nt-load variant regressed to 78.2us (nt demotes the read stream on
// gfx950) — reverted.
//
// Structure: two passes, 402 MB total HBM traffic ~= 62us roofline + launch
// gap. Pass 1 reads x once (134 MB), computes exact-f32 stats via an
// XOR-swizzled LDS tile (conflict-free row + transpose reads), and writes an
// fp16 copy of x to workspace (67 MB). Pass 2 reduces the batch partials
// in-block, applies the momentum/affine math, reads the fp16 copy (67 MB)
// and writes out (134 MB, nontemporal).
//
// Alternatives closed empirically over r1-r16: fused single kernel with grid
// barrier (correct but an invariant ~1.1TB/s throttle: spill/coop/spin/I$/
// occupancy all refuted as causes); L3 producer->consumer reuse (3x refuted);
// reverse-order LRU exploitation (neutral); nt-load steering (regressed).
// ===========================================================================
__global__ __launch_bounds__(256) void mfb_stats(
    const float* __restrict__ x, const float* __restrict__ mask,
    float* __restrict__ mean_bf, float* __restrict__ var_bf,
    unsigned short* __restrict__ hws) {
  __shared__ float tile[NN * NN];  // 64 KB, reused for block reduction
  const int tid = threadIdx.x;
  const int bf = blockIdx.x;
  const int b = bf >> 6;
  const float* xp = x + (size_t)bf * (NN * NN);
  unsigned short* hp = hws + (size_t)bf * (NN * NN);
  const int lane = tid & 63;

  float m0 = mask[b * NN + lane];
  float m1 = mask[b * NN + 64 + lane];
  float msq0 = m0 * m0;
  float msq1 = m1 * m1;

  const int kcol = tid & 127;
  const int ib = tid >> 7;  // 0 or 1
#pragma unroll 8
  for (int c = 0; c < 64; ++c) {
    int i = 2 * c + ib;
    float v = xp[c * 256 + tid];
    tile[i * NN + (kcol ^ (i & 31))] = v;
    hp[c * 256 + tid] = f2h(v);
  }
  __syncthreads();

  float tr = 0.f, nump = 0.f;
  if (tid < 64) nump = msq0 + msq1;  // count num once (wave 0 only)
  if (tid < 128) {
    float d = tile[tid * NN + (tid ^ (tid & 31))];  // diagonal x[i,i]
    tr = d * ((tid < 64) ? msq0 : msq1);
  }

  // trace of x@x: each thread owns half of row irow (64 columns)
  const int irow = tid >> 1;
  const int k0 = (tid & 1) << 6;
  float mq = (irow < 64) ? __shfl(msq0, irow, 64) : __shfl(msq1, irow - 64, 64);
  const int cxor = irow & 31;
  const int rowbase = irow * NN;
  float acc = 0.f;
#pragma unroll
  for (int c = 0; c < 64; ++c) {
    int k = k0 + c;
    float a = tile[rowbase + (k ^ cxor)];          // x[irow, k]
    float bt = tile[k * NN + (irow ^ (k & 31))];   // x[k, irow]
    acc = fmaf(a, bt, acc);
  }
  float trsq = acc * mq;

#pragma unroll
  for (int off = 32; off > 0; off >>= 1) {
    tr   += __shfl_down(tr, off, 64);
    trsq += __shfl_down(trsq, off, 64);
    nump += __shfl_down(nump, off, 64);
  }
  __syncthreads();
  if (lane == 0) {
    int w = tid >> 6;
    tile[w * 3 + 0] = tr;
    tile[w * 3 + 1] = trsq;
    tile[w * 3 + 2] = nump;
  }
  __syncthreads();
  if (tid == 0) {
    float trs = tile[0] + tile[3] + tile[6] + tile[9];
    float tq  = tile[1] + tile[4] + tile[7] + tile[10];
    float num = tile[2] + tile[5] + tile[8] + tile[11];
    float num2 = fmaxf(num - 1.f, 1.f);
    mean_bf[bf] = trs / num;
    var_bf[bf]  = tq / num2 - trs * trs / (num * num2);
  }
}

__global__ __launch_bounds__(256) void mfb_apply(
    const unsigned short* __restrict__ hws, const float* __restrict__ mask,
    const float* __restrict__ mean_bf, const float* __restrict__ var_bf,
    const float* __restrict__ w, const float* __restrict__ wexp,
    const float* __restrict__ wbias, const float* __restrict__ bias,
    const float* __restrict__ rmean, const float* __restrict__ rvar,
    const int* __restrict__ steps, f32x4* __restrict__ out4) {
  const int bf = blockIdx.x;
  const int b = bf >> 6;
  const int f = bf & 63;
  const int tid = threadIdx.x;
  __shared__ float smask[NN];
  __shared__ float sc[3];  // rm, s, bias[f]

  if (tid < NN) smask[tid] = mask[b * NN + tid];
  if (tid < 32) {
    float ms = mean_bf[tid * NF + f];
    float vs = var_bf[tid * NF + f];
#pragma unroll
    for (int off = 16; off > 0; off >>= 1) {
      ms += __shfl_down(ms, off, 32);
      vs += __shfl_down(vs, off, 32);
    }
    if (tid == 0) {
      ms *= (1.f / NB);
      vs *= (1.f / NB);
      int st = steps[0];
      float mom = 0.997f;
      if (st < 100) {
        float beta = (float)st * 0.01f;
        mom = 0.997f * beta + 0.8f * (1.f - beta);
      }
      float rm = mom * rmean[f] + (1.f - mom) * ms;
      float rv = mom * rvar[f] + (1.f - mom) * vs;
      float gain = w[f] * expf(wexp[f]) + wbias[f];
      sc[0] = rm;
      sc[1] = gain / (sqrtf(rv) + EPSF);
      sc[2] = bias[f];
    }
  }
  __syncthreads();

  const float rm = sc[0];
  const float s = sc[1];
  const float bi = sc[2];
  const f32x4 mj4 = ((const f32x4*)smask)[tid & 31];
  const int j0 = (tid & 31) << 2;
  const int wv = tid >> 5;
  const u16x4* hp = (const u16x4*)hws + (size_t)bf * 4096;
  f32x4* op = out4 + (size_t)bf * 4096;

#pragma unroll
  for (int c = 0; c < 16; ++c) {
    const int idx = c * 256 + tid;
    const int i = c * 8 + wv;
    u16x4 hv = hp[idx];
    float x0 = h2f(hv.x), x1 = h2f(hv.y), x2 = h2f(hv.z), x3 = h2f(hv.w);
    float cs = smask[i] * s;
    f32x4 o;
    o.x = (x0 - ((i == j0    ) ? rm : 0.f)) * (cs * mj4.x) + ((i == j0    ) ? bi : 0.f);
    o.y = (x1 - ((i == j0 + 1) ? rm : 0.f)) * (cs * mj4.y) + ((i == j0 + 1) ? bi : 0.f);
    o.z = (x2 - ((i == j0 + 2) ? rm : 0.f)) * (cs * mj4.z) + ((i == j0 + 2) ? bi : 0.f);
    o.w = (x3 - ((i == j0 + 3) ? rm : 0.f)) * (cs * mj4.w) + ((i == j0 + 3) ? bi : 0.f);
    __builtin_nontemporal_store(o, &op[idx]);
  }
}

extern "C" void kernel_launch(void* const* d_in, const int* in_sizes, int n_in,
                              void* d_out, int out_size, void* d_ws, size_t ws_size,
                              hipStream_t stream) {
  const float* x     = (const float*)d_in[0];
  const float* mask  = (const float*)d_in[1];
  const float* w     = (const float*)d_in[2];
  const float* wexp  = (const float*)d_in[3];
  const float* wbias = (const float*)d_in[4];
  const float* bias  = (const float*)d_in[5];
  const float* rmean = (const float*)d_in[6];
  const float* rvar  = (const float*)d_in[7];
  const int*   steps = (const int*)d_in[8];

  float* ws = (float*)d_ws;
  float* mean_bf = ws;                        // [B*F] f32
  float* var_bf  = ws + NB * NF;              // [B*F] f32
  unsigned short* hws = (unsigned short*)(ws + 2 * NB * NF);  // fp16 x copy

  mfb_stats<<<NB * NF, 256, 0, stream>>>(x, mask, mean_bf, var_bf, hws);
  mfb_apply<<<NB * NF, 256, 0, stream>>>(hws, mask, mean_bf, var_bf, w, wexp,
                                         wbias, bias, rmean, rvar, steps,
                                         (f32x4*)d_out);
}